// Round 1
// 821.631 us; speedup vs baseline: 1.2017x; 1.2017x over previous
//
#include <hip/hip_runtime.h>

#define NSs 100000
#define NIi 20000
#define DD  128
#define E1e 600000
#define E2e 500000

typedef __attribute__((ext_vector_type(8))) __bf16 bf16x8;
typedef __attribute__((ext_vector_type(4))) __bf16 bf16x4;
typedef __attribute__((ext_vector_type(2))) __bf16 bf16x2;
typedef __attribute__((ext_vector_type(4))) float  floatx4;

// Async global->LDS 16B copy: LDS dest is wave-uniform base + lane*16,
// global src is per-lane. (guide §5: global_load_lds width=16)
__device__ __forceinline__ void async_copy16(void* lds, const void* gsrc)
{
    __builtin_amdgcn_global_load_lds(
        (const __attribute__((address_space(1))) void*)gsrc,
        (__attribute__((address_space(3))) void*)lds, 16, 0, 0);
}

// ===========================================================================
// CSR build (once per call, reused by both layers).
// ===========================================================================
__global__ __launch_bounds__(256) void hist_kernel(
    const int* __restrict__ dst, int* __restrict__ cnt, int E)
{
    int e = blockIdx.x * 256 + threadIdx.x;
    if (e < E) atomicAdd(cnt + dst[e], 1);
}

__global__ __launch_bounds__(256) void ticket_kernel(
    const int* __restrict__ cnt, int* __restrict__ start,
    int* __restrict__ fill, int* __restrict__ total, int n)
{
    int i    = blockIdx.x * 256 + threadIdx.x;
    int lane = threadIdx.x & 63;
    int c    = (i < n) ? cnt[i] : 0;
    int sum  = c;                       // wave-inclusive scan
#pragma unroll
    for (int ofs = 1; ofs < 64; ofs <<= 1) {
        int up = __shfl_up(sum, ofs, 64);
        if (lane >= ofs) sum += up;
    }
    int wtot = __shfl(sum, 63, 64);
    int base = 0;
    if (lane == 63) base = atomicAdd(total, wtot);
    base = __shfl(base, 63, 64);
    if (i < n) {
        int st = base + sum - c;        // exclusive within wave
        start[i] = st;
        fill[i]  = st;
    }
}

__global__ __launch_bounds__(256) void fill_kernel(
    const int* __restrict__ src, const int* __restrict__ dst,
    int* __restrict__ fill, int* __restrict__ eidx, int E)
{
    int e = blockIdx.x * 256 + threadIdx.x;
    if (e < E) {
        int pos = atomicAdd(fill + dst[e], 1);
        eidx[pos] = src[e];
    }
}

// ===========================================================================
// Gather-aggregate: one wave per dst row; lane owns 2 columns. Accumulate f32
// (identical to before), write bf16 XOR-swizzled: 16B chunk c of row r lands
// at physical chunk c ^ (r&15). Consumed only by the MFMA GEMMs, whose LDS
// staging is a LINEAR global_load_lds copy (swizzle pre-applied here).
// Numerics: bit-identical to old path (gemm converted the same f32 value to
// bf16 during staging anyway).
// ===========================================================================
template <bool MEAN>
__global__ __launch_bounds__(256) void gather_kernel(
    const float* __restrict__ x,
    const int* __restrict__ start,
    const int* __restrict__ end,
    const int* __restrict__ eidx,
    __bf16* __restrict__ agg,
    int n_dst)
{
    long gid = (long)blockIdx.x * 256 + threadIdx.x;
    int d    = (int)(gid >> 6);
    int lane = (int)(gid & 63);
    if (d >= n_dst) return;
    int s0 = start[d], s1 = end[d];
    float2 acc = {0.f, 0.f};
    int i = s0;
    for (; i + 1 < s1; i += 2) {            // 2-way unroll: overlap row loads
        int r0 = eidx[i], r1 = eidx[i + 1];
        float2 v0 = *(const float2*)(x + (size_t)r0 * DD + lane * 2);
        float2 v1 = *(const float2*)(x + (size_t)r1 * DD + lane * 2);
        acc.x += v0.x + v1.x;
        acc.y += v0.y + v1.y;
    }
    if (i < s1) {
        int r0 = eidx[i];
        float2 v0 = *(const float2*)(x + (size_t)r0 * DD + lane * 2);
        acc.x += v0.x;
        acc.y += v0.y;
    }
    if (MEAN) {
        int c = s1 - s0;
        float inv = 1.0f / (float)(c > 1 ? c : 1);
        acc.x *= inv;
        acc.y *= inv;
    }
    // lane owns logical cols 2*lane, 2*lane+1 -> logical chunk lane>>2,
    // within-chunk element (lane&3)*2. Swizzle chunk by row&15.
    int phys = (((lane >> 2) ^ (d & 15)) << 3) + ((lane & 3) << 1);
    bf16x2 o = { (__bf16)acc.x, (__bf16)acc.y };
    *(bf16x2*)(agg + (size_t)d * DD + phys) = o;
}

// ---------------------------------------------------------------------------
// Weights f32 -> packed bf16: [Wl_ri | Wr_ri | Wl_rs | Wr_rs | W_p] x 32768.
// ---------------------------------------------------------------------------
__global__ __launch_bounds__(256) void cvt_weights(
    const float* __restrict__ a, const float* __restrict__ b,
    const float* __restrict__ c, const float* __restrict__ d,
    const float* __restrict__ e, __bf16* __restrict__ out)
{
    int i = blockIdx.x * 256 + threadIdx.x;   // grid covers 5*32768
    const float* srcs[5] = {a, b, c, d, e};
    int which = i >> 15;
    int idx   = i & 32767;
    out[i] = (__bf16)srcs[which][idx];
}

// ===========================================================================
// Student GEMM (MFMA): out = 0.5*( agg@Wl.T + xs@Wr.T + sim@Wp.T + bl + bp )
// v2: latency-tolerant structure.
//  - agg/sim already bf16-swizzled in global -> fire-and-forget
//    global_load_lds (16KB each, linear copy, zero VGPR cost).
//  - xs (f32) reg-staged in two phases (8 loads batched, then 8 cvt+ds_write)
//    into the same swizzled layout.
//  - waves split over OUTPUT COLUMNS (wave owns 32 cols x 64 rows): B-weight
//    fragments loaded ONCE per wave (24 loads vs 96), batched 8-deep in regs.
//  - afrag ds_read_b128 on the XOR-swizzled layout: 2 lanes/bank = free.
// ===========================================================================
#define BM 64

__global__ __launch_bounds__(256) void gemm_stu(
    const __bf16* __restrict__ aggb,
    const float*  xs,                 // may alias out!
    const __bf16* __restrict__ simb,
    const __bf16* __restrict__ Wl,
    const __bf16* __restrict__ Wr,
    const __bf16* __restrict__ Wp,
    const float*  __restrict__ bl,
    const float*  __restrict__ bp,
    float* out,
    int M)
{
    __shared__ __align__(16) __bf16 Aagg[BM * DD];
    __shared__ __align__(16) __bf16 Axs [BM * DD];
    __shared__ __align__(16) __bf16 Asim[BM * DD];

    int tid  = threadIdx.x;
    int lane = tid & 63;
    int wv   = tid >> 6;
    int row0 = blockIdx.x * BM;

    // --- async stage agg+sim: 16 chunks of 1KB each, wave wv does 4 ---
    {
        const char* ga = (const char*)(aggb + (size_t)row0 * DD) + lane * 16;
        const char* gs = (const char*)(simb + (size_t)row0 * DD) + lane * 16;
#pragma unroll
        for (int j = 0; j < 4; ++j) {
            int ch = (wv * 4 + j) * 1024;        // wave-uniform LDS offset
            async_copy16((char*)Aagg + ch, ga + ch);
            async_copy16((char*)Asim + ch, gs + ch);
        }
    }

    // --- reg-stage xs f32 -> bf16 swizzled (two phases for MLP) ---
    {
        floatx4 v[8];
#pragma unroll
        for (int j = 0; j < 8; ++j) {
            int i  = tid + j * 256;
            int r  = i >> 5;
            int gr = row0 + r; if (gr > M - 1) gr = M - 1;
            v[j] = *(const floatx4*)(xs + (size_t)gr * DD + (i & 31) * 4);
        }
#pragma unroll
        for (int j = 0; j < 8; ++j) {
            int i = tid + j * 256;
            int r = i >> 5;
            int h = i & 31;                      // 8B half-chunk within row
            bf16x4 o = { (__bf16)v[j].x, (__bf16)v[j].y,
                         (__bf16)v[j].z, (__bf16)v[j].w };
            int phys = (((h >> 1) ^ (r & 15)) << 4) + ((h & 1) << 3);
            *(bf16x4*)((char*)Axs + r * 256 + phys) = o;
        }
    }
    asm volatile("s_waitcnt vmcnt(0)" ::: "memory");  // gload_lds drain
    __syncthreads();

    int mrow = lane & 15;
    int hi   = lane >> 4;

    floatx4 acc[4][2];
#pragma unroll
    for (int a = 0; a < 4; ++a) {
        acc[a][0] = (floatx4){0.f, 0.f, 0.f, 0.f};
        acc[a][1] = (floatx4){0.f, 0.f, 0.f, 0.f};
    }

    const __bf16* Ws[3] = {Wl, Wr, Wp};
    const __bf16* Am[3] = {Aagg, Axs, Asim};

#pragma unroll
    for (int m = 0; m < 3; ++m) {
        // B fragments for this wave's 2 column tiles, all K: 8 loads batched
        bf16x8 bfr[2][4];
#pragma unroll
        for (int ct2 = 0; ct2 < 2; ++ct2) {
            int brow = (wv * 2 + ct2) * 16 + mrow;
#pragma unroll
            for (int kc = 0; kc < 4; ++kc)
                bfr[ct2][kc] = *(const bf16x8*)(Ws[m] + (size_t)brow * DD + kc * 32 + hi * 8);
        }
        const char* A = (const char*)Am[m];
#pragma unroll
        for (int rt = 0; rt < 4; ++rt) {
            const char* Ar = A + (rt * 16 + mrow) * 256;
#pragma unroll
            for (int kc = 0; kc < 4; ++kc) {
                bf16x8 afr = *(const bf16x8*)(Ar + (((kc * 4 + hi) ^ mrow) << 4));
                acc[rt][0] = __builtin_amdgcn_mfma_f32_16x16x32_bf16(afr, bfr[0][kc], acc[rt][0], 0, 0, 0);
                acc[rt][1] = __builtin_amdgcn_mfma_f32_16x16x32_bf16(afr, bfr[1][kc], acc[rt][1], 0, 0, 0);
            }
        }
    }

#pragma unroll
    for (int ct2 = 0; ct2 < 2; ++ct2) {
        int col  = (wv * 2 + ct2) * 16 + mrow;
        float bb = bl[col] + bp[col];
#pragma unroll
        for (int rt = 0; rt < 4; ++rt) {
#pragma unroll
            for (int r = 0; r < 4; ++r) {
                int grow = row0 + rt * 16 + hi * 4 + r;
                if (grow < M)
                    out[(size_t)grow * DD + col] = 0.5f * (acc[rt][ct2][r] + bb);
            }
        }
    }
}

// ---------------------------------------------------------------------------
// Item GEMM (MFMA): pre = agg@Wl.T + xi@Wr.T + bl ; out = elu(pre) (f32)
// Same v2 structure, 2 matrices.
// ---------------------------------------------------------------------------
__global__ __launch_bounds__(256) void gemm_item(
    const __bf16* __restrict__ aggb,
    const float*  __restrict__ xi,
    const __bf16* __restrict__ Wl,
    const __bf16* __restrict__ Wr,
    const float*  __restrict__ bl,
    float* __restrict__ out,
    int M)
{
    __shared__ __align__(16) __bf16 Aagg[BM * DD];
    __shared__ __align__(16) __bf16 Axi [BM * DD];

    int tid  = threadIdx.x;
    int lane = tid & 63;
    int wv   = tid >> 6;
    int row0 = blockIdx.x * BM;

    {
        const char* ga = (const char*)(aggb + (size_t)row0 * DD) + lane * 16;
#pragma unroll
        for (int j = 0; j < 4; ++j) {
            int ch = (wv * 4 + j) * 1024;
            async_copy16((char*)Aagg + ch, ga + ch);
        }
    }
    {
        floatx4 v[8];
#pragma unroll
        for (int j = 0; j < 8; ++j) {
            int i  = tid + j * 256;
            int r  = i >> 5;
            int gr = row0 + r; if (gr > M - 1) gr = M - 1;
            v[j] = *(const floatx4*)(xi + (size_t)gr * DD + (i & 31) * 4);
        }
#pragma unroll
        for (int j = 0; j < 8; ++j) {
            int i = tid + j * 256;
            int r = i >> 5;
            int h = i & 31;
            bf16x4 o = { (__bf16)v[j].x, (__bf16)v[j].y,
                         (__bf16)v[j].z, (__bf16)v[j].w };
            int phys = (((h >> 1) ^ (r & 15)) << 4) + ((h & 1) << 3);
            *(bf16x4*)((char*)Axi + r * 256 + phys) = o;
        }
    }
    asm volatile("s_waitcnt vmcnt(0)" ::: "memory");
    __syncthreads();

    int mrow = lane & 15;
    int hi   = lane >> 4;

    floatx4 acc[4][2];
#pragma unroll
    for (int a = 0; a < 4; ++a) {
        acc[a][0] = (floatx4){0.f, 0.f, 0.f, 0.f};
        acc[a][1] = (floatx4){0.f, 0.f, 0.f, 0.f};
    }

    const __bf16* Ws[2] = {Wl, Wr};
    const __bf16* Am[2] = {Aagg, Axi};

#pragma unroll
    for (int m = 0; m < 2; ++m) {
        bf16x8 bfr[2][4];
#pragma unroll
        for (int ct2 = 0; ct2 < 2; ++ct2) {
            int brow = (wv * 2 + ct2) * 16 + mrow;
#pragma unroll
            for (int kc = 0; kc < 4; ++kc)
                bfr[ct2][kc] = *(const bf16x8*)(Ws[m] + (size_t)brow * DD + kc * 32 + hi * 8);
        }
        const char* A = (const char*)Am[m];
#pragma unroll
        for (int rt = 0; rt < 4; ++rt) {
            const char* Ar = A + (rt * 16 + mrow) * 256;
#pragma unroll
            for (int kc = 0; kc < 4; ++kc) {
                bf16x8 afr = *(const bf16x8*)(Ar + (((kc * 4 + hi) ^ mrow) << 4));
                acc[rt][0] = __builtin_amdgcn_mfma_f32_16x16x32_bf16(afr, bfr[0][kc], acc[rt][0], 0, 0, 0);
                acc[rt][1] = __builtin_amdgcn_mfma_f32_16x16x32_bf16(afr, bfr[1][kc], acc[rt][1], 0, 0, 0);
            }
        }
    }

#pragma unroll
    for (int ct2 = 0; ct2 < 2; ++ct2) {
        int col  = (wv * 2 + ct2) * 16 + mrow;
        float bb = bl[col];
#pragma unroll
        for (int rt = 0; rt < 4; ++rt) {
#pragma unroll
            for (int r = 0; r < 4; ++r) {
                int grow = row0 + rt * 16 + hi * 4 + r;
                if (grow < M) {
                    float vv = acc[rt][ct2][r] + bb;
                    vv = (vv > 0.f) ? vv : expm1f(vv);
                    out[(size_t)grow * DD + col] = vv;
                }
            }
        }
    }
}

// ---------------------------------------------------------------------------
__global__ __launch_bounds__(256) void bn_stats(
    const float* __restrict__ x, int M,
    float* __restrict__ mout, float* __restrict__ rout)
{
    int n   = blockIdx.x;
    int tid = threadIdx.x;
    float s = 0.f, s2 = 0.f;
    for (int i = tid; i < M; i += 256) {
        float v = x[(size_t)i * DD + n];
        s += v; s2 += v * v;
    }
    __shared__ float ls[256], ls2[256];
    ls[tid] = s; ls2[tid] = s2;
    __syncthreads();
    for (int ofs = 128; ofs > 0; ofs >>= 1) {
        if (tid < ofs) { ls[tid] += ls[tid + ofs]; ls2[tid] += ls2[tid + ofs]; }
        __syncthreads();
    }
    if (tid == 0) {
        float m = ls[0] / (float)M;
        float v = ls2[0] / (float)M - m * m;
        mout[n] = m;
        rout[n] = rsqrtf(v + 1e-5f);
    }
}

__global__ __launch_bounds__(256) void bn_norm(
    const float* __restrict__ x,
    const float* __restrict__ m,
    const float* __restrict__ r,
    const float* __restrict__ g,
    const float* __restrict__ b,
    float* __restrict__ out,
    int M)
{
    int i = blockIdx.x * 256 + threadIdx.x;
    if (i >= M * 32) return;
    int row = i >> 5;
    int c4  = (i & 31) << 2;
    floatx4 v = *(const floatx4*)(x + (size_t)row * DD + c4);
    floatx4 o;
    o.x = (v.x - m[c4 + 0]) * r[c4 + 0] * g[c4 + 0] + b[c4 + 0];
    o.y = (v.y - m[c4 + 1]) * r[c4 + 1] * g[c4 + 1] + b[c4 + 1];
    o.z = (v.z - m[c4 + 2]) * r[c4 + 2] * g[c4 + 2] + b[c4 + 2];
    o.w = (v.w - m[c4 + 3]) * r[c4 + 3] * g[c4 + 3] + b[c4 + 3];
    *(floatx4*)(out + (size_t)row * DD + c4) = o;
}

// ---------------------------------------------------------------------------
extern "C" void kernel_launch(void* const* d_in, const int* in_sizes, int n_in,
                              void* d_out, int out_size, void* d_ws, size_t ws_size,
                              hipStream_t stream)
{
    const float* x_student = (const float*)d_in[0];
    const float* x_item    = (const float*)d_in[1];
    const float* Wl_ri     = (const float*)d_in[2];
    const float* bl_ri     = (const float*)d_in[3];
    const float* Wr_ri     = (const float*)d_in[4];
    const float* Wl_rs     = (const float*)d_in[5];
    const float* bl_rs     = (const float*)d_in[6];
    const float* Wr_rs     = (const float*)d_in[7];
    const float* W_p       = (const float*)d_in[8];
    const float* b_p       = (const float*)d_in[9];
    const float* bn_g      = (const float*)d_in[10];
    const float* bn_b      = (const float*)d_in[11];
    const int* resp_src = (const int*)d_in[12];
    const int* resp_dst = (const int*)d_in[13];
    const int* rev_src  = (const int*)d_in[14];
    const int* rev_dst  = (const int*)d_in[15];
    const int* prec_src = (const int*)d_in[16];
    const int* prec_dst = (const int*)d_in[17];

    // ---- workspace ----
    char* ws = (char*)d_ws;
    size_t off = 0;
    auto alloc = [&](size_t bytes) -> void* {
        void* p = ws + off;
        off += (bytes + 1023) & ~(size_t)1023;
        return p;
    };
    // zeroed region: CSR counts + totals
    int* cnt_r  = (int*)alloc(NIi * 4);
    int* cnt_v  = (int*)alloc(NSs * 4);
    int* cnt_p  = (int*)alloc(NSs * 4);
    int* totals = (int*)alloc(3 * 4);
    size_t zero_bytes = off;
    // CSR arrays
    int* start_r = (int*)alloc(NIi * 4);
    int* fill_r  = (int*)alloc(NIi * 4);
    int* start_v = (int*)alloc(NSs * 4);
    int* fill_v  = (int*)alloc(NSs * 4);
    int* start_p = (int*)alloc(NSs * 4);
    int* fill_p  = (int*)alloc(NSs * 4);
    int* eidx_r  = (int*)alloc((size_t)E1e * 4);
    int* eidx_v  = (int*)alloc((size_t)E1e * 4);
    int* eidx_p  = (int*)alloc((size_t)E2e * 4);
    // aggregation buffers: bf16 swizzled, padded +64 rows so the last GEMM
    // block's async stage stays inside the workspace (garbage rows discarded
    // by the epilogue row guard).
    __bf16* aggb_s = (__bf16*)alloc((size_t)(NSs + 64) * DD * 2);  // 25.6 MB
    __bf16* simb_s = (__bf16*)alloc((size_t)(NSs + 64) * DD * 2);  // 25.6 MB
    __bf16* aggb_i = (__bf16*)alloc((size_t)(NIi + 64) * DD * 2);  //  5.1 MB
    __bf16* wbf  = (__bf16*)alloc((size_t)5 * 32768 * 2);
    float* bn_m  = (float*)alloc(512);
    float* bn_r  = (float*)alloc(512);
    // xi_tmp aliases aggb_s (10.24 MB f32 < 25.6 MB): aggb_s is consumed by
    // gemm_stu BEFORE gemm_item writes xi_tmp; xi_tmp is consumed by bn_*
    // before the next layer's gather rewrites aggb_s.
    float* xi_tmp = (float*)aggb_s;
    (void)ws_size; (void)in_sizes; (void)n_in; (void)out_size;

    float* out_xi = (float*)d_out;                    // xi_1 then xi_2
    float* out_xs = out_xi + (size_t)NIi * DD;        // xs_1 then xs_2

    const int he1 = (E1e + 255) / 256, he2 = (E2e + 255) / 256;
    const int tni = (NIi + 255) / 256, tns = (NSs + 255) / 256;
    const int g_i = (int)(((long)NIi * 64 + 255) / 256);
    const int g_s = (int)(((long)NSs * 64 + 255) / 256);
    const int gi_blocks  = (NIi + BM - 1) / BM;
    const int gs_blocks  = (NSs + BM - 1) / BM;
    const int bnn_blocks = (NIi * 32 + 255) / 256;

    cvt_weights<<<640, 256, 0, stream>>>(Wl_ri, Wr_ri, Wl_rs, Wr_rs, W_p, wbf);
    __bf16* wb_l_ri = wbf + 0 * 32768;
    __bf16* wb_r_ri = wbf + 1 * 32768;
    __bf16* wb_l_rs = wbf + 2 * 32768;
    __bf16* wb_r_rs = wbf + 3 * 32768;
    __bf16* wb_p    = wbf + 4 * 32768;

    // ---- CSR build (once per call, shared by both layers) ----
    hipMemsetAsync(ws, 0, zero_bytes, stream);
    hist_kernel<<<he1, 256, 0, stream>>>(resp_dst, cnt_r, E1e);
    hist_kernel<<<he1, 256, 0, stream>>>(rev_dst,  cnt_v, E1e);
    hist_kernel<<<he2, 256, 0, stream>>>(prec_dst, cnt_p, E2e);
    ticket_kernel<<<tni, 256, 0, stream>>>(cnt_r, start_r, fill_r, totals + 0, NIi);
    ticket_kernel<<<tns, 256, 0, stream>>>(cnt_v, start_v, fill_v, totals + 1, NSs);
    ticket_kernel<<<tns, 256, 0, stream>>>(cnt_p, start_p, fill_p, totals + 2, NSs);
    fill_kernel<<<he1, 256, 0, stream>>>(resp_src, resp_dst, fill_r, eidx_r, E1e);
    fill_kernel<<<he1, 256, 0, stream>>>(rev_src,  rev_dst,  fill_v, eidx_v, E1e);
    fill_kernel<<<he2, 256, 0, stream>>>(prec_src, prec_dst, fill_p, eidx_p, E2e);

    for (int l = 0; l < 2; l++) {
        const float* xs_cur = (l == 0) ? x_student : out_xs;
        const float* xi_cur = (l == 0) ? x_item    : out_xi;
        size_t wOfs = (size_t)l * DD * DD;
        size_t bOfs = (size_t)l * DD;

        gather_kernel<true><<<g_i, 256, 0, stream>>>(xs_cur, start_r, fill_r, eidx_r, aggb_i, NIi);
        gather_kernel<true><<<g_s, 256, 0, stream>>>(xi_cur, start_v, fill_v, eidx_v, aggb_s, NSs);
        gather_kernel<false><<<g_s, 256, 0, stream>>>(xs_cur, start_p, fill_p, eidx_p, simb_s, NSs);

        // student first (consumes aggb_s before gemm_item reuses it as xi_tmp;
        // layer 2: xs_cur aliases out_xs, block-local rows only)
        gemm_stu<<<gs_blocks, 256, 0, stream>>>(aggb_s, xs_cur, simb_s,
                                                wb_l_rs + wOfs, wb_r_rs + wOfs, wb_p + wOfs,
                                                bl_rs + bOfs, b_p + bOfs,
                                                out_xs, NSs);

        gemm_item<<<gi_blocks, 256, 0, stream>>>(aggb_i, xi_cur,
                                                 wb_l_ri + wOfs, wb_r_ri + wOfs, bl_ri + bOfs,
                                                 xi_tmp, NIi);
        bn_stats<<<DD, 256, 0, stream>>>(xi_tmp, NIi, bn_m, bn_r);
        bn_norm<<<bnn_blocks, 256, 0, stream>>>(xi_tmp, bn_m, bn_r,
                                                bn_g + bOfs, bn_b + bOfs, out_xi, NIi);
    }
}

// Round 2
// 708.041 us; speedup vs baseline: 1.3945x; 1.1604x over previous
//
#include <hip/hip_runtime.h>

#define NSs 100000
#define NIi 20000
#define DD  128
#define E1e 600000
#define E2e 500000

typedef __attribute__((ext_vector_type(8))) __bf16 bf16x8;
typedef __attribute__((ext_vector_type(4))) __bf16 bf16x4;
typedef __attribute__((ext_vector_type(2))) __bf16 bf16x2;
typedef __attribute__((ext_vector_type(4))) float  floatx4;

// Async global->LDS 16B copy: LDS dest is wave-uniform base + lane*16,
// global src is per-lane. (guide §5: global_load_lds width=16)
__device__ __forceinline__ void async_copy16(void* lds, const void* gsrc)
{
    __builtin_amdgcn_global_load_lds(
        (const __attribute__((address_space(1))) void*)gsrc,
        (__attribute__((address_space(3))) void*)lds, 16, 0, 0);
}

// ===========================================================================
// CSR build (once per call, reused by both layers).
// ===========================================================================
__global__ __launch_bounds__(256) void hist_kernel(
    const int* __restrict__ dst, int* __restrict__ cnt, int E)
{
    int e = blockIdx.x * 256 + threadIdx.x;
    if (e < E) atomicAdd(cnt + dst[e], 1);
}

__global__ __launch_bounds__(256) void ticket_kernel(
    const int* __restrict__ cnt, int* __restrict__ start,
    int* __restrict__ fill, int* __restrict__ total, int n)
{
    int i    = blockIdx.x * 256 + threadIdx.x;
    int lane = threadIdx.x & 63;
    int c    = (i < n) ? cnt[i] : 0;
    int sum  = c;                       // wave-inclusive scan
#pragma unroll
    for (int ofs = 1; ofs < 64; ofs <<= 1) {
        int up = __shfl_up(sum, ofs, 64);
        if (lane >= ofs) sum += up;
    }
    int wtot = __shfl(sum, 63, 64);
    int base = 0;
    if (lane == 63) base = atomicAdd(total, wtot);
    base = __shfl(base, 63, 64);
    if (i < n) {
        int st = base + sum - c;        // exclusive within wave
        start[i] = st;
        fill[i]  = st;
    }
}

__global__ __launch_bounds__(256) void fill_kernel(
    const int* __restrict__ src, const int* __restrict__ dst,
    int* __restrict__ fill, int* __restrict__ eidx, int E)
{
    int e = blockIdx.x * 256 + threadIdx.x;
    if (e < E) {
        int pos = atomicAdd(fill + dst[e], 1);
        eidx[pos] = src[e];
    }
}

// ===========================================================================
// Gather-aggregate v3: HALF-WAVE per dst row (32 lanes x float4 = 128 cols).
//  - neighbor indices batch-loaded (one coalesced load per <=32 neighbors),
//    broadcast via width-32 shfl -> no eidx->row dependent chain.
//  - row loads 8-deep in flight (4/2/1 tail) -> latency-bound fix.
// Output bf16, XOR-swizzled chunks (chunk c of row r at c ^ (r&15)), matching
// the GEMM's linear global_load_lds staging.
// ===========================================================================
template <bool MEAN>
__global__ __launch_bounds__(256) void gather_kernel(
    const float* __restrict__ x,
    const int* __restrict__ start,
    const int* __restrict__ end,
    const int* __restrict__ eidx,
    __bf16* __restrict__ agg,
    int n_dst)
{
    long gid = (long)blockIdx.x * 256 + threadIdx.x;
    int d   = (int)(gid >> 5);          // half-wave per dst row
    int sub = (int)(gid & 31);
    if (d >= n_dst) return;
    int s0 = start[d], s1 = end[d];
    int deg = s1 - s0;
    floatx4 acc = {0.f, 0.f, 0.f, 0.f};
    const float* xl = x + sub * 4;
    int base = s0;
    while (base < s1) {
        int chunk = s1 - base; if (chunk > 32) chunk = 32;
        int my_e = eidx[base + (sub < chunk ? sub : chunk - 1)];
        int j = 0;
        for (; j + 8 <= chunk; j += 8) {
            int r0 = __shfl(my_e, j + 0, 32);
            int r1 = __shfl(my_e, j + 1, 32);
            int r2 = __shfl(my_e, j + 2, 32);
            int r3 = __shfl(my_e, j + 3, 32);
            int r4 = __shfl(my_e, j + 4, 32);
            int r5 = __shfl(my_e, j + 5, 32);
            int r6 = __shfl(my_e, j + 6, 32);
            int r7 = __shfl(my_e, j + 7, 32);
            floatx4 v0 = *(const floatx4*)(xl + (size_t)r0 * DD);
            floatx4 v1 = *(const floatx4*)(xl + (size_t)r1 * DD);
            floatx4 v2 = *(const floatx4*)(xl + (size_t)r2 * DD);
            floatx4 v3 = *(const floatx4*)(xl + (size_t)r3 * DD);
            floatx4 v4 = *(const floatx4*)(xl + (size_t)r4 * DD);
            floatx4 v5 = *(const floatx4*)(xl + (size_t)r5 * DD);
            floatx4 v6 = *(const floatx4*)(xl + (size_t)r6 * DD);
            floatx4 v7 = *(const floatx4*)(xl + (size_t)r7 * DD);
            acc += ((v0 + v1) + (v2 + v3)) + ((v4 + v5) + (v6 + v7));
        }
        if (j + 4 <= chunk) {
            int r0 = __shfl(my_e, j + 0, 32);
            int r1 = __shfl(my_e, j + 1, 32);
            int r2 = __shfl(my_e, j + 2, 32);
            int r3 = __shfl(my_e, j + 3, 32);
            floatx4 v0 = *(const floatx4*)(xl + (size_t)r0 * DD);
            floatx4 v1 = *(const floatx4*)(xl + (size_t)r1 * DD);
            floatx4 v2 = *(const floatx4*)(xl + (size_t)r2 * DD);
            floatx4 v3 = *(const floatx4*)(xl + (size_t)r3 * DD);
            acc += (v0 + v1) + (v2 + v3);
            j += 4;
        }
        if (j + 2 <= chunk) {
            int r0 = __shfl(my_e, j + 0, 32);
            int r1 = __shfl(my_e, j + 1, 32);
            floatx4 v0 = *(const floatx4*)(xl + (size_t)r0 * DD);
            floatx4 v1 = *(const floatx4*)(xl + (size_t)r1 * DD);
            acc += v0 + v1;
            j += 2;
        }
        if (j < chunk) {
            int r0 = __shfl(my_e, j, 32);
            floatx4 v0 = *(const floatx4*)(xl + (size_t)r0 * DD);
            acc += v0;
        }
        base += chunk;
    }
    if (MEAN) {
        float inv = 1.0f / (float)(deg > 1 ? deg : 1);
        acc.x *= inv; acc.y *= inv; acc.z *= inv; acc.w *= inv;
    }
    bf16x4 o = { (__bf16)acc.x, (__bf16)acc.y, (__bf16)acc.z, (__bf16)acc.w };
    int phys = (((sub >> 1) ^ (d & 15)) << 4) + ((sub & 1) << 3);   // bytes
    *(bf16x4*)((char*)(agg + (size_t)d * DD) + phys) = o;
}

// ---------------------------------------------------------------------------
// Weights f32 -> packed bf16: [Wl_ri | Wr_ri | Wl_rs | Wr_rs | W_p] x 32768.
// ---------------------------------------------------------------------------
__global__ __launch_bounds__(256) void cvt_weights(
    const float* __restrict__ a, const float* __restrict__ b,
    const float* __restrict__ c, const float* __restrict__ d,
    const float* __restrict__ e, __bf16* __restrict__ out)
{
    int i = blockIdx.x * 256 + threadIdx.x;   // grid covers 5*32768
    const float* srcs[5] = {a, b, c, d, e};
    int which = i >> 15;
    int idx   = i & 32767;
    out[i] = (__bf16)srcs[which][idx];
}

// ===========================================================================
// Student GEMM (MFMA): out = 0.5*( agg@Wl.T + xs@Wr.T + sim@Wp.T + bl + bp )
// ===========================================================================
#define BM 64

__global__ __launch_bounds__(256) void gemm_stu(
    const __bf16* __restrict__ aggb,
    const float*  xs,                 // may alias out!
    const __bf16* __restrict__ simb,
    const __bf16* __restrict__ Wl,
    const __bf16* __restrict__ Wr,
    const __bf16* __restrict__ Wp,
    const float*  __restrict__ bl,
    const float*  __restrict__ bp,
    float* out,
    int M)
{
    __shared__ __align__(16) __bf16 Aagg[BM * DD];
    __shared__ __align__(16) __bf16 Axs [BM * DD];
    __shared__ __align__(16) __bf16 Asim[BM * DD];

    int tid  = threadIdx.x;
    int lane = tid & 63;
    int wv   = tid >> 6;
    int row0 = blockIdx.x * BM;

    // --- async stage agg+sim: 16 chunks of 1KB each, wave wv does 4 ---
    {
        const char* ga = (const char*)(aggb + (size_t)row0 * DD) + lane * 16;
        const char* gs = (const char*)(simb + (size_t)row0 * DD) + lane * 16;
#pragma unroll
        for (int j = 0; j < 4; ++j) {
            int ch = (wv * 4 + j) * 1024;        // wave-uniform LDS offset
            async_copy16((char*)Aagg + ch, ga + ch);
            async_copy16((char*)Asim + ch, gs + ch);
        }
    }

    // --- reg-stage xs f32 -> bf16 swizzled (two phases for MLP) ---
    {
        floatx4 v[8];
#pragma unroll
        for (int j = 0; j < 8; ++j) {
            int i  = tid + j * 256;
            int r  = i >> 5;
            int gr = row0 + r; if (gr > M - 1) gr = M - 1;
            v[j] = *(const floatx4*)(xs + (size_t)gr * DD + (i & 31) * 4);
        }
#pragma unroll
        for (int j = 0; j < 8; ++j) {
            int i = tid + j * 256;
            int r = i >> 5;
            int h = i & 31;                      // 8B half-chunk within row
            bf16x4 o = { (__bf16)v[j].x, (__bf16)v[j].y,
                         (__bf16)v[j].z, (__bf16)v[j].w };
            int phys = (((h >> 1) ^ (r & 15)) << 4) + ((h & 1) << 3);
            *(bf16x4*)((char*)Axs + r * 256 + phys) = o;
        }
    }
    asm volatile("s_waitcnt vmcnt(0)" ::: "memory");  // gload_lds drain
    __syncthreads();

    int mrow = lane & 15;
    int hi   = lane >> 4;

    floatx4 acc[4][2];
#pragma unroll
    for (int a = 0; a < 4; ++a) {
        acc[a][0] = (floatx4){0.f, 0.f, 0.f, 0.f};
        acc[a][1] = (floatx4){0.f, 0.f, 0.f, 0.f};
    }

    const __bf16* Ws[3] = {Wl, Wr, Wp};
    const __bf16* Am[3] = {Aagg, Axs, Asim};

#pragma unroll
    for (int m = 0; m < 3; ++m) {
        // B fragments for this wave's 2 column tiles, all K: 8 loads batched
        bf16x8 bfr[2][4];
#pragma unroll
        for (int ct2 = 0; ct2 < 2; ++ct2) {
            int brow = (wv * 2 + ct2) * 16 + mrow;
#pragma unroll
            for (int kc = 0; kc < 4; ++kc)
                bfr[ct2][kc] = *(const bf16x8*)(Ws[m] + (size_t)brow * DD + kc * 32 + hi * 8);
        }
        const char* A = (const char*)Am[m];
#pragma unroll
        for (int rt = 0; rt < 4; ++rt) {
            const char* Ar = A + (rt * 16 + mrow) * 256;
#pragma unroll
            for (int kc = 0; kc < 4; ++kc) {
                bf16x8 afr = *(const bf16x8*)(Ar + (((kc * 4 + hi) ^ mrow) << 4));
                acc[rt][0] = __builtin_amdgcn_mfma_f32_16x16x32_bf16(afr, bfr[0][kc], acc[rt][0], 0, 0, 0);
                acc[rt][1] = __builtin_amdgcn_mfma_f32_16x16x32_bf16(afr, bfr[1][kc], acc[rt][1], 0, 0, 0);
            }
        }
    }

#pragma unroll
    for (int ct2 = 0; ct2 < 2; ++ct2) {
        int col  = (wv * 2 + ct2) * 16 + mrow;
        float bb = bl[col] + bp[col];
#pragma unroll
        for (int rt = 0; rt < 4; ++rt) {
#pragma unroll
            for (int r = 0; r < 4; ++r) {
                int grow = row0 + rt * 16 + hi * 4 + r;
                if (grow < M)
                    out[(size_t)grow * DD + col] = 0.5f * (acc[rt][ct2][r] + bb);
            }
        }
    }
}

// ---------------------------------------------------------------------------
// Item GEMM (MFMA): pre = agg@Wl.T + xi@Wr.T + bl ; out = elu(pre) (f32)
// v3: BN column stats (sum, sumsq) fused into epilogue -> bn_stats kernel
// eliminated (its column-strided reads over-fetched 16x).
// ---------------------------------------------------------------------------
__global__ __launch_bounds__(256) void gemm_item(
    const __bf16* __restrict__ aggb,
    const float*  __restrict__ xi,
    const __bf16* __restrict__ Wl,
    const __bf16* __restrict__ Wr,
    const float*  __restrict__ bl,
    float* __restrict__ out,
    float* __restrict__ col_sum,
    float* __restrict__ col_sum2,
    int M)
{
    __shared__ __align__(16) __bf16 Aagg[BM * DD];
    __shared__ __align__(16) __bf16 Axi [BM * DD];

    int tid  = threadIdx.x;
    int lane = tid & 63;
    int wv   = tid >> 6;
    int row0 = blockIdx.x * BM;

    {
        const char* ga = (const char*)(aggb + (size_t)row0 * DD) + lane * 16;
#pragma unroll
        for (int j = 0; j < 4; ++j) {
            int ch = (wv * 4 + j) * 1024;
            async_copy16((char*)Aagg + ch, ga + ch);
        }
    }
    {
        floatx4 v[8];
#pragma unroll
        for (int j = 0; j < 8; ++j) {
            int i  = tid + j * 256;
            int r  = i >> 5;
            int gr = row0 + r; if (gr > M - 1) gr = M - 1;
            v[j] = *(const floatx4*)(xi + (size_t)gr * DD + (i & 31) * 4);
        }
#pragma unroll
        for (int j = 0; j < 8; ++j) {
            int i = tid + j * 256;
            int r = i >> 5;
            int h = i & 31;
            bf16x4 o = { (__bf16)v[j].x, (__bf16)v[j].y,
                         (__bf16)v[j].z, (__bf16)v[j].w };
            int phys = (((h >> 1) ^ (r & 15)) << 4) + ((h & 1) << 3);
            *(bf16x4*)((char*)Axi + r * 256 + phys) = o;
        }
    }
    asm volatile("s_waitcnt vmcnt(0)" ::: "memory");
    __syncthreads();

    int mrow = lane & 15;
    int hi   = lane >> 4;

    floatx4 acc[4][2];
#pragma unroll
    for (int a = 0; a < 4; ++a) {
        acc[a][0] = (floatx4){0.f, 0.f, 0.f, 0.f};
        acc[a][1] = (floatx4){0.f, 0.f, 0.f, 0.f};
    }

    const __bf16* Ws[2] = {Wl, Wr};
    const __bf16* Am[2] = {Aagg, Axi};

#pragma unroll
    for (int m = 0; m < 2; ++m) {
        bf16x8 bfr[2][4];
#pragma unroll
        for (int ct2 = 0; ct2 < 2; ++ct2) {
            int brow = (wv * 2 + ct2) * 16 + mrow;
#pragma unroll
            for (int kc = 0; kc < 4; ++kc)
                bfr[ct2][kc] = *(const bf16x8*)(Ws[m] + (size_t)brow * DD + kc * 32 + hi * 8);
        }
        const char* A = (const char*)Am[m];
#pragma unroll
        for (int rt = 0; rt < 4; ++rt) {
            const char* Ar = A + (rt * 16 + mrow) * 256;
#pragma unroll
            for (int kc = 0; kc < 4; ++kc) {
                bf16x8 afr = *(const bf16x8*)(Ar + (((kc * 4 + hi) ^ mrow) << 4));
                acc[rt][0] = __builtin_amdgcn_mfma_f32_16x16x32_bf16(afr, bfr[0][kc], acc[rt][0], 0, 0, 0);
                acc[rt][1] = __builtin_amdgcn_mfma_f32_16x16x32_bf16(afr, bfr[1][kc], acc[rt][1], 0, 0, 0);
            }
        }
    }

#pragma unroll
    for (int ct2 = 0; ct2 < 2; ++ct2) {
        int col  = (wv * 2 + ct2) * 16 + mrow;
        float bb = bl[col];
        float s = 0.f, s2 = 0.f;
#pragma unroll
        for (int rt = 0; rt < 4; ++rt) {
#pragma unroll
            for (int r = 0; r < 4; ++r) {
                int grow = row0 + rt * 16 + hi * 4 + r;
                if (grow < M) {
                    float vv = acc[rt][ct2][r] + bb;
                    vv = (vv > 0.f) ? vv : expm1f(vv);
                    out[(size_t)grow * DD + col] = vv;
                    s += vv; s2 += vv * vv;
                }
            }
        }
        // reduce across the 4 hi-groups (lanes mrow, +16, +32, +48): same col
        s  += __shfl_xor(s, 16);  s2 += __shfl_xor(s2, 16);
        s  += __shfl_xor(s, 32);  s2 += __shfl_xor(s2, 32);
        if (hi == 0) {
            atomicAdd(col_sum  + col, s);
            atomicAdd(col_sum2 + col, s2);
        }
    }
}

// ---------------------------------------------------------------------------
// BN normalize: mean/rsqrt finalized inline from fused column sums.
// ---------------------------------------------------------------------------
__global__ __launch_bounds__(256) void bn_norm(
    const float* __restrict__ x,
    const float* __restrict__ cs,
    const float* __restrict__ cs2,
    const float* __restrict__ g,
    const float* __restrict__ b,
    float* __restrict__ out,
    int M)
{
    int i = blockIdx.x * 256 + threadIdx.x;
    if (i >= M * 32) return;
    int row = i >> 5;
    int c4  = (i & 31) << 2;
    float invM = 1.0f / (float)M;
    floatx4 v = *(const floatx4*)(x + (size_t)row * DD + c4);
    floatx4 o;
#pragma unroll
    for (int k = 0; k < 4; ++k) {
        float m = cs[c4 + k] * invM;
        float r = rsqrtf(cs2[c4 + k] * invM - m * m + 1e-5f);
        o[k] = (v[k] - m) * r * g[c4 + k] + b[c4 + k];
    }
    *(floatx4*)(out + (size_t)row * DD + c4) = o;
}

// ---------------------------------------------------------------------------
extern "C" void kernel_launch(void* const* d_in, const int* in_sizes, int n_in,
                              void* d_out, int out_size, void* d_ws, size_t ws_size,
                              hipStream_t stream)
{
    const float* x_student = (const float*)d_in[0];
    const float* x_item    = (const float*)d_in[1];
    const float* Wl_ri     = (const float*)d_in[2];
    const float* bl_ri     = (const float*)d_in[3];
    const float* Wr_ri     = (const float*)d_in[4];
    const float* Wl_rs     = (const float*)d_in[5];
    const float* bl_rs     = (const float*)d_in[6];
    const float* Wr_rs     = (const float*)d_in[7];
    const float* W_p       = (const float*)d_in[8];
    const float* b_p       = (const float*)d_in[9];
    const float* bn_g      = (const float*)d_in[10];
    const float* bn_b      = (const float*)d_in[11];
    const int* resp_src = (const int*)d_in[12];
    const int* resp_dst = (const int*)d_in[13];
    const int* rev_src  = (const int*)d_in[14];
    const int* rev_dst  = (const int*)d_in[15];
    const int* prec_src = (const int*)d_in[16];
    const int* prec_dst = (const int*)d_in[17];

    // ---- workspace ----
    char* ws = (char*)d_ws;
    size_t off = 0;
    auto alloc = [&](size_t bytes) -> void* {
        void* p = ws + off;
        off += (bytes + 1023) & ~(size_t)1023;
        return p;
    };
    // zeroed region: CSR counts + totals + fused BN column stats (per layer)
    int* cnt_r  = (int*)alloc(NIi * 4);
    int* cnt_v  = (int*)alloc(NSs * 4);
    int* cnt_p  = (int*)alloc(NSs * 4);
    int* totals = (int*)alloc(3 * 4);
    float* cstat = (float*)alloc(4 * 128 * 4);   // [l0 sum|l0 sum2|l1 sum|l1 sum2]
    size_t zero_bytes = off;
    // CSR arrays
    int* start_r = (int*)alloc(NIi * 4);
    int* fill_r  = (int*)alloc(NIi * 4);
    int* start_v = (int*)alloc(NSs * 4);
    int* fill_v  = (int*)alloc(NSs * 4);
    int* start_p = (int*)alloc(NSs * 4);
    int* fill_p  = (int*)alloc(NSs * 4);
    int* eidx_r  = (int*)alloc((size_t)E1e * 4);
    int* eidx_v  = (int*)alloc((size_t)E1e * 4);
    int* eidx_p  = (int*)alloc((size_t)E2e * 4);
    // aggregation buffers: bf16 swizzled, padded +64 rows for the last GEMM
    // block's async stage overrun (garbage rows discarded by row guard).
    __bf16* aggb_s = (__bf16*)alloc((size_t)(NSs + 64) * DD * 2);  // 25.6 MB
    __bf16* simb_s = (__bf16*)alloc((size_t)(NSs + 64) * DD * 2);  // 25.6 MB
    __bf16* aggb_i = (__bf16*)alloc((size_t)(NIi + 64) * DD * 2);  //  5.1 MB
    __bf16* wbf  = (__bf16*)alloc((size_t)5 * 32768 * 2);
    // xi_tmp aliases aggb_s (10.24 MB f32 < 25.6 MB): aggb_s is consumed by
    // gemm_stu BEFORE gemm_item writes xi_tmp; xi_tmp is consumed by bn_norm
    // before the next layer's gather rewrites aggb_s.
    float* xi_tmp = (float*)aggb_s;
    (void)ws_size; (void)in_sizes; (void)n_in; (void)out_size;

    float* out_xi = (float*)d_out;                    // xi_1 then xi_2
    float* out_xs = out_xi + (size_t)NIi * DD;        // xs_1 then xs_2

    const int he1 = (E1e + 255) / 256, he2 = (E2e + 255) / 256;
    const int tni = (NIi + 255) / 256, tns = (NSs + 255) / 256;
    const int g_i = (int)(((long)NIi * 32 + 255) / 256);
    const int g_s = (int)(((long)NSs * 32 + 255) / 256);
    const int gi_blocks  = (NIi + BM - 1) / BM;
    const int gs_blocks  = (NSs + BM - 1) / BM;
    const int bnn_blocks = (NIi * 32 + 255) / 256;

    cvt_weights<<<640, 256, 0, stream>>>(Wl_ri, Wr_ri, Wl_rs, Wr_rs, W_p, wbf);
    __bf16* wb_l_ri = wbf + 0 * 32768;
    __bf16* wb_r_ri = wbf + 1 * 32768;
    __bf16* wb_l_rs = wbf + 2 * 32768;
    __bf16* wb_r_rs = wbf + 3 * 32768;
    __bf16* wb_p    = wbf + 4 * 32768;

    // ---- CSR build (once per call, shared by both layers) ----
    hipMemsetAsync(ws, 0, zero_bytes, stream);
    hist_kernel<<<he1, 256, 0, stream>>>(resp_dst, cnt_r, E1e);
    hist_kernel<<<he1, 256, 0, stream>>>(rev_dst,  cnt_v, E1e);
    hist_kernel<<<he2, 256, 0, stream>>>(prec_dst, cnt_p, E2e);
    ticket_kernel<<<tni, 256, 0, stream>>>(cnt_r, start_r, fill_r, totals + 0, NIi);
    ticket_kernel<<<tns, 256, 0, stream>>>(cnt_v, start_v, fill_v, totals + 1, NSs);
    ticket_kernel<<<tns, 256, 0, stream>>>(cnt_p, start_p, fill_p, totals + 2, NSs);
    fill_kernel<<<he1, 256, 0, stream>>>(resp_src, resp_dst, fill_r, eidx_r, E1e);
    fill_kernel<<<he1, 256, 0, stream>>>(rev_src,  rev_dst,  fill_v, eidx_v, E1e);
    fill_kernel<<<he2, 256, 0, stream>>>(prec_src, prec_dst, fill_p, eidx_p, E2e);

    for (int l = 0; l < 2; l++) {
        const float* xs_cur = (l == 0) ? x_student : out_xs;
        const float* xi_cur = (l == 0) ? x_item    : out_xi;
        size_t wOfs = (size_t)l * DD * DD;
        size_t bOfs = (size_t)l * DD;
        float* cs  = cstat + (size_t)l * 256;
        float* cs2 = cs + 128;

        gather_kernel<true><<<g_i, 256, 0, stream>>>(xs_cur, start_r, fill_r, eidx_r, aggb_i, NIi);
        gather_kernel<true><<<g_s, 256, 0, stream>>>(xi_cur, start_v, fill_v, eidx_v, aggb_s, NSs);
        gather_kernel<false><<<g_s, 256, 0, stream>>>(xs_cur, start_p, fill_p, eidx_p, simb_s, NSs);

        // student first (consumes aggb_s before gemm_item reuses it as xi_tmp;
        // layer 2: xs_cur aliases out_xs, block-local rows only)
        gemm_stu<<<gs_blocks, 256, 0, stream>>>(aggb_s, xs_cur, simb_s,
                                                wb_l_rs + wOfs, wb_r_rs + wOfs, wb_p + wOfs,
                                                bl_rs + bOfs, b_p + bOfs,
                                                out_xs, NSs);

        gemm_item<<<gi_blocks, 256, 0, stream>>>(aggb_i, xi_cur,
                                                 wb_l_ri + wOfs, wb_r_ri + wOfs, bl_ri + bOfs,
                                                 xi_tmp, cs, cs2, NIi);
        bn_norm<<<bnn_blocks, 256, 0, stream>>>(xi_tmp, cs, cs2,
                                                bn_g + bOfs, bn_b + bOfs, out_xi, NIi);
    }
}

// Round 3
// 636.894 us; speedup vs baseline: 1.5503x; 1.1117x over previous
//
#include <hip/hip_runtime.h>

#define NSs 100000
#define NIi 20000
#define DD  128
#define E1e 600000
#define E2e 500000

typedef __attribute__((ext_vector_type(8))) __bf16 bf16x8;
typedef __attribute__((ext_vector_type(4))) __bf16 bf16x4;
typedef __attribute__((ext_vector_type(4))) float  floatx4;

// Async global->LDS 16B copy: LDS dest is wave-uniform base + lane*16,
// global src is per-lane. (guide §5: global_load_lds width=16)
__device__ __forceinline__ void async_copy16(void* lds, const void* gsrc)
{
    __builtin_amdgcn_global_load_lds(
        (const __attribute__((address_space(1))) void*)gsrc,
        (__attribute__((address_space(3))) void*)lds, 16, 0, 0);
}

__device__ __forceinline__ floatx4 cvt4(bf16x4 v)
{
    return (floatx4){ (float)v.x, (float)v.y, (float)v.z, (float)v.w };
}

// Swizzled-row addressing: 16B chunk c of row r lives at chunk c ^ (r&15).
// Row stride 256 B (128 bf16).
__device__ __forceinline__ const char* swz_addr(
    const __bf16* tab, int r, int c16, int c8)
{
    return (const char*)tab + (size_t)r * 256 + (((c16 ^ (r & 15)) << 4) | c8);
}

// ===========================================================================
// CSR build (once per call, reused by both layers).
// ===========================================================================
__global__ __launch_bounds__(256) void hist_kernel(
    const int* __restrict__ dst, int* __restrict__ cnt, int E)
{
    int e = blockIdx.x * 256 + threadIdx.x;
    if (e < E) atomicAdd(cnt + dst[e], 1);
}

__global__ __launch_bounds__(256) void ticket_kernel(
    const int* __restrict__ cnt, int* __restrict__ start,
    int* __restrict__ fill, int* __restrict__ total, int n)
{
    int i    = blockIdx.x * 256 + threadIdx.x;
    int lane = threadIdx.x & 63;
    int c    = (i < n) ? cnt[i] : 0;
    int sum  = c;                       // wave-inclusive scan
#pragma unroll
    for (int ofs = 1; ofs < 64; ofs <<= 1) {
        int up = __shfl_up(sum, ofs, 64);
        if (lane >= ofs) sum += up;
    }
    int wtot = __shfl(sum, 63, 64);
    int base = 0;
    if (lane == 63) base = atomicAdd(total, wtot);
    base = __shfl(base, 63, 64);
    if (i < n) {
        int st = base + sum - c;        // exclusive within wave
        start[i] = st;
        fill[i]  = st;
    }
}

__global__ __launch_bounds__(256) void fill_kernel(
    const int* __restrict__ src, const int* __restrict__ dst,
    int* __restrict__ fill, int* __restrict__ eidx, int E)
{
    int e = blockIdx.x * 256 + threadIdx.x;
    if (e < E) {
        int pos = atomicAdd(fill + dst[e], 1);
        eidx[pos] = src[e];
    }
}

// ===========================================================================
// x f32 row-major -> bf16 swizzled table (layer-0 inputs only; layer-1
// tables are written fused in the GEMM / BN epilogues).
// ===========================================================================
__global__ __launch_bounds__(256) void cvt_x(
    const float* __restrict__ in, __bf16* __restrict__ out, int M)
{
    int i = blockIdx.x * 256 + threadIdx.x;     // one 16B chunk per thread
    if (i >= M * 16) return;
    int r = i >> 4, c = i & 15;
    const float* p = in + (size_t)r * DD + c * 8;
    floatx4 a = *(const floatx4*)p;
    floatx4 b = *(const floatx4*)(p + 4);
    bf16x8 o = { (__bf16)a.x, (__bf16)a.y, (__bf16)a.z, (__bf16)a.w,
                 (__bf16)b.x, (__bf16)b.y, (__bf16)b.z, (__bf16)b.w };
    *(bf16x8*)((char*)out + (size_t)r * 256 + ((c ^ (r & 15)) << 4)) = o;
}

// ===========================================================================
// Gather-aggregate v4: bf16 swizzled source rows (256 B). Half-wave per dst
// row (32 lanes x 8 B). Neighbor indices batch-loaded + shfl-broadcast; row
// loads 16-deep in flight. f32 accumulate; output bf16 swizzled.
// ===========================================================================
template <bool MEAN>
__global__ __launch_bounds__(256) void gather_kernel(
    const __bf16* __restrict__ x,
    const int* __restrict__ start,
    const int* __restrict__ end,
    const int* __restrict__ eidx,
    __bf16* __restrict__ agg,
    int n_dst)
{
    long gid = (long)blockIdx.x * 256 + threadIdx.x;
    int d   = (int)(gid >> 5);          // half-wave per dst row
    int sub = (int)(gid & 31);
    if (d >= n_dst) return;
    int c16 = sub >> 1;                 // this lane's logical 16B chunk
    int c8  = (sub & 1) << 3;           // 8B half within chunk
    int s0 = start[d], s1 = end[d];
    int deg = s1 - s0;
    floatx4 acc = {0.f, 0.f, 0.f, 0.f};
    int base = s0;
    while (base < s1) {
        int chunk = s1 - base; if (chunk > 32) chunk = 32;
        int my_e = eidx[base + (sub < chunk ? sub : chunk - 1)];
        int j = 0;
        for (; j + 16 <= chunk; j += 16) {
            bf16x4 v[16];
#pragma unroll
            for (int k = 0; k < 16; ++k) {
                int rr = __shfl(my_e, j + k, 32);
                v[k] = *(const bf16x4*)swz_addr(x, rr, c16, c8);
            }
            floatx4 t0 = (cvt4(v[0]) + cvt4(v[1])) + (cvt4(v[2]) + cvt4(v[3]));
            floatx4 t1 = (cvt4(v[4]) + cvt4(v[5])) + (cvt4(v[6]) + cvt4(v[7]));
            floatx4 t2 = (cvt4(v[8]) + cvt4(v[9])) + (cvt4(v[10]) + cvt4(v[11]));
            floatx4 t3 = (cvt4(v[12]) + cvt4(v[13])) + (cvt4(v[14]) + cvt4(v[15]));
            acc += (t0 + t1) + (t2 + t3);
        }
        if (j + 8 <= chunk) {
            bf16x4 v[8];
#pragma unroll
            for (int k = 0; k < 8; ++k) {
                int rr = __shfl(my_e, j + k, 32);
                v[k] = *(const bf16x4*)swz_addr(x, rr, c16, c8);
            }
            acc += ((cvt4(v[0]) + cvt4(v[1])) + (cvt4(v[2]) + cvt4(v[3]))) +
                   ((cvt4(v[4]) + cvt4(v[5])) + (cvt4(v[6]) + cvt4(v[7])));
            j += 8;
        }
        if (j + 4 <= chunk) {
            bf16x4 v[4];
#pragma unroll
            for (int k = 0; k < 4; ++k) {
                int rr = __shfl(my_e, j + k, 32);
                v[k] = *(const bf16x4*)swz_addr(x, rr, c16, c8);
            }
            acc += (cvt4(v[0]) + cvt4(v[1])) + (cvt4(v[2]) + cvt4(v[3]));
            j += 4;
        }
        if (j + 2 <= chunk) {
            int r0 = __shfl(my_e, j + 0, 32);
            int r1 = __shfl(my_e, j + 1, 32);
            bf16x4 v0 = *(const bf16x4*)swz_addr(x, r0, c16, c8);
            bf16x4 v1 = *(const bf16x4*)swz_addr(x, r1, c16, c8);
            acc += cvt4(v0) + cvt4(v1);
            j += 2;
        }
        if (j < chunk) {
            int r0 = __shfl(my_e, j, 32);
            acc += cvt4(*(const bf16x4*)swz_addr(x, r0, c16, c8));
        }
        base += chunk;
    }
    if (MEAN) {
        float inv = 1.0f / (float)(deg > 1 ? deg : 1);
        acc.x *= inv; acc.y *= inv; acc.z *= inv; acc.w *= inv;
    }
    bf16x4 o = { (__bf16)acc.x, (__bf16)acc.y, (__bf16)acc.z, (__bf16)acc.w };
    *(bf16x4*)((char*)agg + (size_t)d * 256 + (((c16 ^ (d & 15)) << 4) | c8)) = o;
}

// ---------------------------------------------------------------------------
// Weights f32 -> packed bf16: [Wl_ri | Wr_ri | Wl_rs | Wr_rs | W_p] x 32768.
// ---------------------------------------------------------------------------
__global__ __launch_bounds__(256) void cvt_weights(
    const float* __restrict__ a, const float* __restrict__ b,
    const float* __restrict__ c, const float* __restrict__ d,
    const float* __restrict__ e, __bf16* __restrict__ out)
{
    int i = blockIdx.x * 256 + threadIdx.x;   // grid covers 5*32768
    const float* srcs[5] = {a, b, c, d, e};
    int which = i >> 15;
    int idx   = i & 32767;
    out[i] = (__bf16)srcs[which][idx];
}

// ===========================================================================
// Student GEMM (MFMA): out = 0.5*( agg@Wl.T + xs@Wr.T + sim@Wp.T + bl + bp )
// v4: ALL three A-operands are bf16 swizzled tables -> pure async staging.
// Optional fused epilogue write of the next layer's bf16 swizzled xs table.
// ===========================================================================
#define BM 64

__global__ __launch_bounds__(256) void gemm_stu(
    const __bf16* __restrict__ aggb,
    const __bf16* __restrict__ xsb,     // may be the same buffer as xsb_out!
    const __bf16* __restrict__ simb,
    const __bf16* __restrict__ Wl,
    const __bf16* __restrict__ Wr,
    const __bf16* __restrict__ Wp,
    const float*  __restrict__ bl,
    const float*  __restrict__ bp,
    float* __restrict__ out,
    __bf16* xsb_out,                    // null for last layer
    int M)
{
    __shared__ __align__(16) __bf16 Aagg[BM * DD];
    __shared__ __align__(16) __bf16 Axs [BM * DD];
    __shared__ __align__(16) __bf16 Asim[BM * DD];

    int tid  = threadIdx.x;
    int lane = tid & 63;
    int wv   = tid >> 6;
    int row0 = blockIdx.x * BM;

    // async stage all three: 16KB each, wave wv stages 4 x 1KB of each
    {
        const char* ga = (const char*)aggb + (size_t)row0 * 256 + lane * 16;
        const char* gx = (const char*)xsb  + (size_t)row0 * 256 + lane * 16;
        const char* gs = (const char*)simb + (size_t)row0 * 256 + lane * 16;
#pragma unroll
        for (int j = 0; j < 4; ++j) {
            int ch = (wv * 4 + j) * 1024;        // wave-uniform LDS offset
            async_copy16((char*)Aagg + ch, ga + ch);
            async_copy16((char*)Axs  + ch, gx + ch);
            async_copy16((char*)Asim + ch, gs + ch);
        }
    }
    asm volatile("s_waitcnt vmcnt(0)" ::: "memory");  // gload_lds drain
    __syncthreads();

    int mrow = lane & 15;
    int hi   = lane >> 4;

    floatx4 acc[4][2];
#pragma unroll
    for (int a = 0; a < 4; ++a) {
        acc[a][0] = (floatx4){0.f, 0.f, 0.f, 0.f};
        acc[a][1] = (floatx4){0.f, 0.f, 0.f, 0.f};
    }

    const __bf16* Ws[3] = {Wl, Wr, Wp};
    const __bf16* Am[3] = {Aagg, Axs, Asim};

#pragma unroll
    for (int m = 0; m < 3; ++m) {
        // B fragments for this wave's 2 column tiles, all K: 8 loads batched
        bf16x8 bfr[2][4];
#pragma unroll
        for (int ct2 = 0; ct2 < 2; ++ct2) {
            int brow = (wv * 2 + ct2) * 16 + mrow;
#pragma unroll
            for (int kc = 0; kc < 4; ++kc)
                bfr[ct2][kc] = *(const bf16x8*)(Ws[m] + (size_t)brow * DD + kc * 32 + hi * 8);
        }
        const char* A = (const char*)Am[m];
#pragma unroll
        for (int rt = 0; rt < 4; ++rt) {
            const char* Ar = A + (rt * 16 + mrow) * 256;
#pragma unroll
            for (int kc = 0; kc < 4; ++kc) {
                bf16x8 afr = *(const bf16x8*)(Ar + (((kc * 4 + hi) ^ mrow) << 4));
                acc[rt][0] = __builtin_amdgcn_mfma_f32_16x16x32_bf16(afr, bfr[0][kc], acc[rt][0], 0, 0, 0);
                acc[rt][1] = __builtin_amdgcn_mfma_f32_16x16x32_bf16(afr, bfr[1][kc], acc[rt][1], 0, 0, 0);
            }
        }
    }

#pragma unroll
    for (int ct2 = 0; ct2 < 2; ++ct2) {
        int col  = (wv * 2 + ct2) * 16 + mrow;
        int cch  = col >> 3;                 // 16B chunk of col
        int cin  = (col & 7) * 2;            // byte within chunk
        float bb = bl[col] + bp[col];
#pragma unroll
        for (int rt = 0; rt < 4; ++rt) {
#pragma unroll
            for (int r = 0; r < 4; ++r) {
                int grow = row0 + rt * 16 + hi * 4 + r;
                if (grow < M) {
                    float v = 0.5f * (acc[rt][ct2][r] + bb);
                    out[(size_t)grow * DD + col] = v;
                    if (xsb_out) {
                        char* p = (char*)xsb_out + (size_t)grow * 256 +
                                  (((cch ^ (grow & 15)) << 4) | cin);
                        *(__bf16*)p = (__bf16)v;
                    }
                }
            }
        }
    }
}

// ---------------------------------------------------------------------------
// Item GEMM (MFMA): pre = agg@Wl.T + xi@Wr.T + bl ; out = elu(pre) (f32)
// BN column stats fused into epilogue. Both A-operands async-staged bf16.
// ---------------------------------------------------------------------------
__global__ __launch_bounds__(256) void gemm_item(
    const __bf16* __restrict__ aggb,
    const __bf16* __restrict__ xib,
    const __bf16* __restrict__ Wl,
    const __bf16* __restrict__ Wr,
    const float*  __restrict__ bl,
    float* __restrict__ out,
    float* __restrict__ col_sum,
    float* __restrict__ col_sum2,
    int M)
{
    __shared__ __align__(16) __bf16 Aagg[BM * DD];
    __shared__ __align__(16) __bf16 Axi [BM * DD];

    int tid  = threadIdx.x;
    int lane = tid & 63;
    int wv   = tid >> 6;
    int row0 = blockIdx.x * BM;

    {
        const char* ga = (const char*)aggb + (size_t)row0 * 256 + lane * 16;
        const char* gx = (const char*)xib  + (size_t)row0 * 256 + lane * 16;
#pragma unroll
        for (int j = 0; j < 4; ++j) {
            int ch = (wv * 4 + j) * 1024;
            async_copy16((char*)Aagg + ch, ga + ch);
            async_copy16((char*)Axi  + ch, gx + ch);
        }
    }
    asm volatile("s_waitcnt vmcnt(0)" ::: "memory");
    __syncthreads();

    int mrow = lane & 15;
    int hi   = lane >> 4;

    floatx4 acc[4][2];
#pragma unroll
    for (int a = 0; a < 4; ++a) {
        acc[a][0] = (floatx4){0.f, 0.f, 0.f, 0.f};
        acc[a][1] = (floatx4){0.f, 0.f, 0.f, 0.f};
    }

    const __bf16* Ws[2] = {Wl, Wr};
    const __bf16* Am[2] = {Aagg, Axi};

#pragma unroll
    for (int m = 0; m < 2; ++m) {
        bf16x8 bfr[2][4];
#pragma unroll
        for (int ct2 = 0; ct2 < 2; ++ct2) {
            int brow = (wv * 2 + ct2) * 16 + mrow;
#pragma unroll
            for (int kc = 0; kc < 4; ++kc)
                bfr[ct2][kc] = *(const bf16x8*)(Ws[m] + (size_t)brow * DD + kc * 32 + hi * 8);
        }
        const char* A = (const char*)Am[m];
#pragma unroll
        for (int rt = 0; rt < 4; ++rt) {
            const char* Ar = A + (rt * 16 + mrow) * 256;
#pragma unroll
            for (int kc = 0; kc < 4; ++kc) {
                bf16x8 afr = *(const bf16x8*)(Ar + (((kc * 4 + hi) ^ mrow) << 4));
                acc[rt][0] = __builtin_amdgcn_mfma_f32_16x16x32_bf16(afr, bfr[0][kc], acc[rt][0], 0, 0, 0);
                acc[rt][1] = __builtin_amdgcn_mfma_f32_16x16x32_bf16(afr, bfr[1][kc], acc[rt][1], 0, 0, 0);
            }
        }
    }

#pragma unroll
    for (int ct2 = 0; ct2 < 2; ++ct2) {
        int col  = (wv * 2 + ct2) * 16 + mrow;
        float bb = bl[col];
        float s = 0.f, s2 = 0.f;
#pragma unroll
        for (int rt = 0; rt < 4; ++rt) {
#pragma unroll
            for (int r = 0; r < 4; ++r) {
                int grow = row0 + rt * 16 + hi * 4 + r;
                if (grow < M) {
                    float vv = acc[rt][ct2][r] + bb;
                    vv = (vv > 0.f) ? vv : expm1f(vv);
                    out[(size_t)grow * DD + col] = vv;
                    s += vv; s2 += vv * vv;
                }
            }
        }
        // reduce across the 4 hi-groups (lanes mrow, +16, +32, +48): same col
        s  += __shfl_xor(s, 16);  s2 += __shfl_xor(s2, 16);
        s  += __shfl_xor(s, 32);  s2 += __shfl_xor(s2, 32);
        if (hi == 0) {
            atomicAdd(col_sum  + col, s);
            atomicAdd(col_sum2 + col, s2);
        }
    }
}

// ---------------------------------------------------------------------------
// BN normalize: mean/rsqrt finalized inline from fused column sums.
// Optionally writes the next layer's bf16 swizzled item table.
// ---------------------------------------------------------------------------
__global__ __launch_bounds__(256) void bn_norm(
    const float* __restrict__ x,
    const float* __restrict__ cs,
    const float* __restrict__ cs2,
    const float* __restrict__ g,
    const float* __restrict__ b,
    float* __restrict__ out,
    __bf16* xib_out,                    // null for last layer
    int M)
{
    int i = blockIdx.x * 256 + threadIdx.x;
    if (i >= M * 32) return;
    int row = i >> 5;
    int h   = i & 31;                   // 8B half-chunk within row
    int c4  = h << 2;
    float invM = 1.0f / (float)M;
    floatx4 v = *(const floatx4*)(x + (size_t)row * DD + c4);
    floatx4 o;
#pragma unroll
    for (int k = 0; k < 4; ++k) {
        float m = cs[c4 + k] * invM;
        float r = rsqrtf(cs2[c4 + k] * invM - m * m + 1e-5f);
        o[k] = (v[k] - m) * r * g[c4 + k] + b[c4 + k];
    }
    *(floatx4*)(out + (size_t)row * DD + c4) = o;
    if (xib_out) {
        bf16x4 ob = { (__bf16)o.x, (__bf16)o.y, (__bf16)o.z, (__bf16)o.w };
        int phys = (((h >> 1) ^ (row & 15)) << 4) | ((h & 1) << 3);
        *(bf16x4*)((char*)xib_out + (size_t)row * 256 + phys) = ob;
    }
}

// ---------------------------------------------------------------------------
extern "C" void kernel_launch(void* const* d_in, const int* in_sizes, int n_in,
                              void* d_out, int out_size, void* d_ws, size_t ws_size,
                              hipStream_t stream)
{
    const float* x_student = (const float*)d_in[0];
    const float* x_item    = (const float*)d_in[1];
    const float* Wl_ri     = (const float*)d_in[2];
    const float* bl_ri     = (const float*)d_in[3];
    const float* Wr_ri     = (const float*)d_in[4];
    const float* Wl_rs     = (const float*)d_in[5];
    const float* bl_rs     = (const float*)d_in[6];
    const float* Wr_rs     = (const float*)d_in[7];
    const float* W_p       = (const float*)d_in[8];
    const float* b_p       = (const float*)d_in[9];
    const float* bn_g      = (const float*)d_in[10];
    const float* bn_b      = (const float*)d_in[11];
    const int* resp_src = (const int*)d_in[12];
    const int* resp_dst = (const int*)d_in[13];
    const int* rev_src  = (const int*)d_in[14];
    const int* rev_dst  = (const int*)d_in[15];
    const int* prec_src = (const int*)d_in[16];
    const int* prec_dst = (const int*)d_in[17];

    // ---- workspace ----
    char* ws = (char*)d_ws;
    size_t off = 0;
    auto alloc = [&](size_t bytes) -> void* {
        void* p = ws + off;
        off += (bytes + 1023) & ~(size_t)1023;
        return p;
    };
    // zeroed region: CSR counts + totals + fused BN column stats (per layer)
    int* cnt_r  = (int*)alloc(NIi * 4);
    int* cnt_v  = (int*)alloc(NSs * 4);
    int* cnt_p  = (int*)alloc(NSs * 4);
    int* totals = (int*)alloc(3 * 4);
    float* cstat = (float*)alloc(4 * 128 * 4);   // [l0 sum|l0 sum2|l1 sum|l1 sum2]
    size_t zero_bytes = off;
    // CSR arrays
    int* start_r = (int*)alloc(NIi * 4);
    int* fill_r  = (int*)alloc(NIi * 4);
    int* start_v = (int*)alloc(NSs * 4);
    int* fill_v  = (int*)alloc(NSs * 4);
    int* start_p = (int*)alloc(NSs * 4);
    int* fill_p  = (int*)alloc(NSs * 4);
    int* eidx_r  = (int*)alloc((size_t)E1e * 4);
    int* eidx_v  = (int*)alloc((size_t)E1e * 4);
    int* eidx_p  = (int*)alloc((size_t)E2e * 4);
    // bf16 swizzled tables & aggregation buffers (+64 rows pad for the last
    // GEMM block's async-stage overrun; garbage rows discarded by row guard).
    __bf16* xsb    = (__bf16*)alloc((size_t)(NSs + 64) * DD * 2);  // 25.6 MB
    __bf16* xib    = (__bf16*)alloc((size_t)(NIi + 64) * DD * 2);  //  5.1 MB
    __bf16* aggb_s = (__bf16*)alloc((size_t)(NSs + 64) * DD * 2);  // 25.6 MB
    __bf16* simb_s = (__bf16*)alloc((size_t)(NSs + 64) * DD * 2);  // 25.6 MB
    __bf16* aggb_i = (__bf16*)alloc((size_t)(NIi + 64) * DD * 2);  //  5.1 MB
    __bf16* wbf  = (__bf16*)alloc((size_t)5 * 32768 * 2);
    // xi_tmp aliases aggb_s (10.24 MB f32 < 25.6 MB): aggb_s is consumed by
    // gemm_stu BEFORE gemm_item writes xi_tmp; xi_tmp is consumed by bn_norm
    // before the next layer's gather rewrites aggb_s.
    float* xi_tmp = (float*)aggb_s;
    (void)ws_size; (void)in_sizes; (void)n_in; (void)out_size;

    float* out_xi = (float*)d_out;                    // xi_1 then xi_2
    float* out_xs = out_xi + (size_t)NIi * DD;        // xs_1 then xs_2

    const int he1 = (E1e + 255) / 256, he2 = (E2e + 255) / 256;
    const int tni = (NIi + 255) / 256, tns = (NSs + 255) / 256;
    const int g_i = (int)(((long)NIi * 32 + 255) / 256);
    const int g_s = (int)(((long)NSs * 32 + 255) / 256);
    const int gi_blocks  = (NIi + BM - 1) / BM;
    const int gs_blocks  = (NSs + BM - 1) / BM;
    const int bnn_blocks = (NIi * 32 + 255) / 256;
    const int cxs_blocks = (NSs * 16 + 255) / 256;
    const int cxi_blocks = (NIi * 16 + 255) / 256;

    cvt_weights<<<640, 256, 0, stream>>>(Wl_ri, Wr_ri, Wl_rs, Wr_rs, W_p, wbf);
    __bf16* wb_l_ri = wbf + 0 * 32768;
    __bf16* wb_r_ri = wbf + 1 * 32768;
    __bf16* wb_l_rs = wbf + 2 * 32768;
    __bf16* wb_r_rs = wbf + 3 * 32768;
    __bf16* wb_p    = wbf + 4 * 32768;

    // layer-0 bf16 swizzled node tables
    cvt_x<<<cxs_blocks, 256, 0, stream>>>(x_student, xsb, NSs);
    cvt_x<<<cxi_blocks, 256, 0, stream>>>(x_item,    xib, NIi);

    // ---- CSR build (once per call, shared by both layers) ----
    hipMemsetAsync(ws, 0, zero_bytes, stream);
    hist_kernel<<<he1, 256, 0, stream>>>(resp_dst, cnt_r, E1e);
    hist_kernel<<<he1, 256, 0, stream>>>(rev_dst,  cnt_v, E1e);
    hist_kernel<<<he2, 256, 0, stream>>>(prec_dst, cnt_p, E2e);
    ticket_kernel<<<tni, 256, 0, stream>>>(cnt_r, start_r, fill_r, totals + 0, NIi);
    ticket_kernel<<<tns, 256, 0, stream>>>(cnt_v, start_v, fill_v, totals + 1, NSs);
    ticket_kernel<<<tns, 256, 0, stream>>>(cnt_p, start_p, fill_p, totals + 2, NSs);
    fill_kernel<<<he1, 256, 0, stream>>>(resp_src, resp_dst, fill_r, eidx_r, E1e);
    fill_kernel<<<he1, 256, 0, stream>>>(rev_src,  rev_dst,  fill_v, eidx_v, E1e);
    fill_kernel<<<he2, 256, 0, stream>>>(prec_src, prec_dst, fill_p, eidx_p, E2e);

    for (int l = 0; l < 2; l++) {
        size_t wOfs = (size_t)l * DD * DD;
        size_t bOfs = (size_t)l * DD;
        float* cs  = cstat + (size_t)l * 256;
        float* cs2 = cs + 128;
        __bf16* xsb_next = (l == 0) ? xsb : nullptr;   // fused epilogue table
        __bf16* xib_next = (l == 0) ? xib : nullptr;

        gather_kernel<true><<<g_i, 256, 0, stream>>>(xsb, start_r, fill_r, eidx_r, aggb_i, NIi);
        gather_kernel<true><<<g_s, 256, 0, stream>>>(xib, start_v, fill_v, eidx_v, aggb_s, NSs);
        gather_kernel<false><<<g_s, 256, 0, stream>>>(xsb, start_p, fill_p, eidx_p, simb_s, NSs);

        // student first (consumes aggb_s before gemm_item reuses it as xi_tmp).
        // l==0: reads xsb rows [row0,row0+64) then overwrites the same rows in
        // the epilogue (block-local, after vmcnt0+barrier) -> safe.
        gemm_stu<<<gs_blocks, 256, 0, stream>>>(aggb_s, xsb, simb_s,
                                                wb_l_rs + wOfs, wb_r_rs + wOfs, wb_p + wOfs,
                                                bl_rs + bOfs, b_p + bOfs,
                                                out_xs, xsb_next, NSs);

        gemm_item<<<gi_blocks, 256, 0, stream>>>(aggb_i, xib,
                                                 wb_l_ri + wOfs, wb_r_ri + wOfs, bl_ri + bOfs,
                                                 xi_tmp, cs, cs2, NIi);
        bn_norm<<<bnn_blocks, 256, 0, stream>>>(xi_tmp, cs, cs2,
                                                bn_g + bOfs, bn_b + bOfs, out_xi,
                                                xib_next, NIi);
    }
}

// Round 4
// 599.713 us; speedup vs baseline: 1.6464x; 1.0620x over previous
//
#include <hip/hip_runtime.h>

#define NSs 100000
#define NIi 20000
#define DD  128
#define E1e 600000
#define E2e 500000

typedef __attribute__((ext_vector_type(8))) __bf16 bf16x8;
typedef __attribute__((ext_vector_type(4))) __bf16 bf16x4;
typedef __attribute__((ext_vector_type(4))) float  floatx4;

// Async global->LDS 16B copy: LDS dest is wave-uniform base + lane*16,
// global src is per-lane. (guide §5: global_load_lds width=16)
__device__ __forceinline__ void async_copy16(void* lds, const void* gsrc)
{
    __builtin_amdgcn_global_load_lds(
        (const __attribute__((address_space(1))) void*)gsrc,
        (__attribute__((address_space(3))) void*)lds, 16, 0, 0);
}

__device__ __forceinline__ floatx4 cvt4(bf16x4 v)
{
    return (floatx4){ (float)v.x, (float)v.y, (float)v.z, (float)v.w };
}

// Swizzled-row addressing: 16B chunk c of row r lives at chunk c ^ (r&15).
// Row stride 256 B (128 bf16).
__device__ __forceinline__ const char* swz_addr(
    const __bf16* tab, int r, int c16, int c8)
{
    return (const char*)tab + (size_t)r * 256 + (((c16 ^ (r & 15)) << 4) | c8);
}

// ===========================================================================
// CSR build (once per call, reused by both layers).
// ===========================================================================
__global__ __launch_bounds__(256) void hist_kernel(
    const int* __restrict__ dst, int* __restrict__ cnt, int E)
{
    int e = blockIdx.x * 256 + threadIdx.x;
    if (e < E) atomicAdd(cnt + dst[e], 1);
}

__global__ __launch_bounds__(256) void ticket_kernel(
    const int* __restrict__ cnt, int* __restrict__ start,
    int* __restrict__ fill, int* __restrict__ total, int n)
{
    int i    = blockIdx.x * 256 + threadIdx.x;
    int lane = threadIdx.x & 63;
    int c    = (i < n) ? cnt[i] : 0;
    int sum  = c;                       // wave-inclusive scan
#pragma unroll
    for (int ofs = 1; ofs < 64; ofs <<= 1) {
        int up = __shfl_up(sum, ofs, 64);
        if (lane >= ofs) sum += up;
    }
    int wtot = __shfl(sum, 63, 64);
    int base = 0;
    if (lane == 63) base = atomicAdd(total, wtot);
    base = __shfl(base, 63, 64);
    if (i < n) {
        int st = base + sum - c;        // exclusive within wave
        start[i] = st;
        fill[i]  = st;
    }
}

__global__ __launch_bounds__(256) void fill_kernel(
    const int* __restrict__ src, const int* __restrict__ dst,
    int* __restrict__ fill, int* __restrict__ eidx, int E)
{
    int e = blockIdx.x * 256 + threadIdx.x;
    if (e < E) {
        int pos = atomicAdd(fill + dst[e], 1);
        eidx[pos] = src[e];
    }
}

// ===========================================================================
// x f32 row-major -> bf16 swizzled table (layer-0 inputs only; layer-1
// tables are written fused in the GEMM / BN epilogues).
// ===========================================================================
__global__ __launch_bounds__(256) void cvt_x(
    const float* __restrict__ in, __bf16* __restrict__ out, int M)
{
    int i = blockIdx.x * 256 + threadIdx.x;     // one 16B chunk per thread
    if (i >= M * 16) return;
    int r = i >> 4, c = i & 15;
    const float* p = in + (size_t)r * DD + c * 8;
    floatx4 a = *(const floatx4*)p;
    floatx4 b = *(const floatx4*)(p + 4);
    bf16x8 o = { (__bf16)a.x, (__bf16)a.y, (__bf16)a.z, (__bf16)a.w,
                 (__bf16)b.x, (__bf16)b.y, (__bf16)b.z, (__bf16)b.w };
    *(bf16x8*)((char*)out + (size_t)r * 256 + ((c ^ (r & 15)) << 4)) = o;
}

// ===========================================================================
// Gather-aggregate body: bf16 swizzled source rows (256 B). Half-wave per
// dst row (32 lanes x 8 B). Neighbor indices batch-loaded + shfl-broadcast;
// row loads 16-deep in flight. f32 accumulate; output bf16 swizzled.
// ===========================================================================
__device__ __forceinline__ void gather_body(
    const __bf16* __restrict__ x,
    const int* __restrict__ start,
    const int* __restrict__ end,
    const int* __restrict__ eidx,
    __bf16* __restrict__ agg,
    int n_dst, bool mean, long gid)
{
    int d   = (int)(gid >> 5);          // half-wave per dst row
    int sub = (int)(gid & 31);
    if (d >= n_dst) return;
    int c16 = sub >> 1;                 // this lane's logical 16B chunk
    int c8  = (sub & 1) << 3;           // 8B half within chunk
    int s0 = start[d], s1 = end[d];
    int deg = s1 - s0;
    floatx4 acc = {0.f, 0.f, 0.f, 0.f};
    int base = s0;
    while (base < s1) {
        int chunk = s1 - base; if (chunk > 32) chunk = 32;
        int my_e = eidx[base + (sub < chunk ? sub : chunk - 1)];
        int j = 0;
        for (; j + 16 <= chunk; j += 16) {
            bf16x4 v[16];
#pragma unroll
            for (int k = 0; k < 16; ++k) {
                int rr = __shfl(my_e, j + k, 32);
                v[k] = *(const bf16x4*)swz_addr(x, rr, c16, c8);
            }
            floatx4 t0 = (cvt4(v[0]) + cvt4(v[1])) + (cvt4(v[2]) + cvt4(v[3]));
            floatx4 t1 = (cvt4(v[4]) + cvt4(v[5])) + (cvt4(v[6]) + cvt4(v[7]));
            floatx4 t2 = (cvt4(v[8]) + cvt4(v[9])) + (cvt4(v[10]) + cvt4(v[11]));
            floatx4 t3 = (cvt4(v[12]) + cvt4(v[13])) + (cvt4(v[14]) + cvt4(v[15]));
            acc += (t0 + t1) + (t2 + t3);
        }
        if (j + 8 <= chunk) {
            bf16x4 v[8];
#pragma unroll
            for (int k = 0; k < 8; ++k) {
                int rr = __shfl(my_e, j + k, 32);
                v[k] = *(const bf16x4*)swz_addr(x, rr, c16, c8);
            }
            acc += ((cvt4(v[0]) + cvt4(v[1])) + (cvt4(v[2]) + cvt4(v[3]))) +
                   ((cvt4(v[4]) + cvt4(v[5])) + (cvt4(v[6]) + cvt4(v[7])));
            j += 8;
        }
        if (j + 4 <= chunk) {
            bf16x4 v[4];
#pragma unroll
            for (int k = 0; k < 4; ++k) {
                int rr = __shfl(my_e, j + k, 32);
                v[k] = *(const bf16x4*)swz_addr(x, rr, c16, c8);
            }
            acc += (cvt4(v[0]) + cvt4(v[1])) + (cvt4(v[2]) + cvt4(v[3]));
            j += 4;
        }
        if (j + 2 <= chunk) {
            int r0 = __shfl(my_e, j + 0, 32);
            int r1 = __shfl(my_e, j + 1, 32);
            bf16x4 v0 = *(const bf16x4*)swz_addr(x, r0, c16, c8);
            bf16x4 v1 = *(const bf16x4*)swz_addr(x, r1, c16, c8);
            acc += cvt4(v0) + cvt4(v1);
            j += 2;
        }
        if (j < chunk) {
            int r0 = __shfl(my_e, j, 32);
            acc += cvt4(*(const bf16x4*)swz_addr(x, r0, c16, c8));
        }
        base += chunk;
    }
    if (mean) {
        float inv = 1.0f / (float)(deg > 1 ? deg : 1);
        acc.x *= inv; acc.y *= inv; acc.z *= inv; acc.w *= inv;
    }
    bf16x4 o = { (__bf16)acc.x, (__bf16)acc.y, (__bf16)acc.z, (__bf16)acc.w };
    *(bf16x4*)((char*)agg + (size_t)d * 256 + (((c16 ^ (d & 15)) << 4) | c8)) = o;
}

// One launch covering all three gathers (machine fill; no launch gaps).
__global__ __launch_bounds__(256) void gather3(
    const __bf16* __restrict__ xsb, const __bf16* __restrict__ xib,
    const int* __restrict__ start_r, const int* __restrict__ end_r, const int* __restrict__ eidx_r,
    const int* __restrict__ start_v, const int* __restrict__ end_v, const int* __restrict__ eidx_v,
    const int* __restrict__ start_p, const int* __restrict__ end_p, const int* __restrict__ eidx_p,
    __bf16* __restrict__ aggb_i, __bf16* __restrict__ aggb_s, __bf16* __restrict__ simb_s,
    int nb_i, int nb_v)
{
    int b = blockIdx.x;
    if (b < nb_i) {
        gather_body(xsb, start_r, end_r, eidx_r, aggb_i, NIi, true,
                    (long)b * 256 + threadIdx.x);
    } else if (b < nb_i + nb_v) {
        gather_body(xib, start_v, end_v, eidx_v, aggb_s, NSs, true,
                    (long)(b - nb_i) * 256 + threadIdx.x);
    } else {
        gather_body(xsb, start_p, end_p, eidx_p, simb_s, NSs, false,
                    (long)(b - nb_i - nb_v) * 256 + threadIdx.x);
    }
}

// ---------------------------------------------------------------------------
// Weights f32 -> packed bf16: [Wl_ri | Wr_ri | Wl_rs | Wr_rs | W_p] x 32768.
// ---------------------------------------------------------------------------
__global__ __launch_bounds__(256) void cvt_weights(
    const float* __restrict__ a, const float* __restrict__ b,
    const float* __restrict__ c, const float* __restrict__ d,
    const float* __restrict__ e, __bf16* __restrict__ out)
{
    int i = blockIdx.x * 256 + threadIdx.x;   // grid covers 5*32768
    const float* srcs[5] = {a, b, c, d, e};
    int which = i >> 15;
    int idx   = i & 32767;
    out[i] = (__bf16)srcs[which][idx];
}

// ===========================================================================
// Fused GEMM dispatch: blocks [0,nb_stu) run the student GEMM, the rest the
// item GEMM (313 item blocks hide inside 1563 stu blocks).
//   stu:  out = 0.5*( agg@Wl.T + xs@Wr.T + sim@Wp.T + bl + bp )
//         l=0: write only next-layer bf16 table (LDS-staged, coalesced 16B).
//         l=1: write only f32 out (l=0 f32 state is dead).
//   item: pre = agg@Wl.T + xi@Wr.T + bl ; out = elu(pre) f32 + fused BN stats.
// ===========================================================================
#define BM 64

__global__ __launch_bounds__(256) void gemm_fused(
    // student
    const __bf16* __restrict__ aggb_s,
    const __bf16* xsb,                  // aliases xsb_out at l=0 (block-local)
    const __bf16* __restrict__ simb,
    const __bf16* __restrict__ Wl_s,
    const __bf16* __restrict__ Wr_s,
    const __bf16* __restrict__ Wp,
    const float*  __restrict__ bl_s,
    const float*  __restrict__ bp,
    float* out_s,                       // null at l=0
    __bf16* xsb_out,                    // null at l=1
    // item
    const __bf16* __restrict__ aggb_i,
    const __bf16* __restrict__ xib,
    const __bf16* __restrict__ Wl_i,
    const __bf16* __restrict__ Wr_i,
    const float*  __restrict__ bl_i,
    float* __restrict__ out_i,
    float* __restrict__ col_sum,
    float* __restrict__ col_sum2,
    int nb_stu)
{
    __shared__ __align__(16) __bf16 A[3][BM * DD];

    int tid  = threadIdx.x;
    int lane = tid & 63;
    int wv   = tid >> 6;
    int mrow = lane & 15;
    int hi   = lane >> 4;

    if (blockIdx.x < nb_stu) {
        // ---------------- student path ----------------
        int row0 = blockIdx.x * BM;
        {
            const char* ga = (const char*)aggb_s + (size_t)row0 * 256 + lane * 16;
            const char* gx = (const char*)xsb    + (size_t)row0 * 256 + lane * 16;
            const char* gs = (const char*)simb   + (size_t)row0 * 256 + lane * 16;
#pragma unroll
            for (int j = 0; j < 4; ++j) {
                int ch = (wv * 4 + j) * 1024;    // wave-uniform LDS offset
                async_copy16((char*)A[0] + ch, ga + ch);
                async_copy16((char*)A[1] + ch, gx + ch);
                async_copy16((char*)A[2] + ch, gs + ch);
            }
        }
        asm volatile("s_waitcnt vmcnt(0)" ::: "memory");
        __syncthreads();

        floatx4 acc[4][2];
#pragma unroll
        for (int a = 0; a < 4; ++a) {
            acc[a][0] = (floatx4){0.f, 0.f, 0.f, 0.f};
            acc[a][1] = (floatx4){0.f, 0.f, 0.f, 0.f};
        }
        const __bf16* Ws[3] = {Wl_s, Wr_s, Wp};
#pragma unroll
        for (int m = 0; m < 3; ++m) {
            bf16x8 bfr[2][4];
#pragma unroll
            for (int ct2 = 0; ct2 < 2; ++ct2) {
                int brow = (wv * 2 + ct2) * 16 + mrow;
#pragma unroll
                for (int kc = 0; kc < 4; ++kc)
                    bfr[ct2][kc] = *(const bf16x8*)(Ws[m] + (size_t)brow * DD + kc * 32 + hi * 8);
            }
            const char* Ab = (const char*)A[m];
#pragma unroll
            for (int rt = 0; rt < 4; ++rt) {
                const char* Ar = Ab + (rt * 16 + mrow) * 256;
#pragma unroll
                for (int kc = 0; kc < 4; ++kc) {
                    bf16x8 afr = *(const bf16x8*)(Ar + (((kc * 4 + hi) ^ mrow) << 4));
                    acc[rt][0] = __builtin_amdgcn_mfma_f32_16x16x32_bf16(afr, bfr[0][kc], acc[rt][0], 0, 0, 0);
                    acc[rt][1] = __builtin_amdgcn_mfma_f32_16x16x32_bf16(afr, bfr[1][kc], acc[rt][1], 0, 0, 0);
                }
            }
        }

        if (out_s) {   // l=1: plain f32 output
#pragma unroll
            for (int ct2 = 0; ct2 < 2; ++ct2) {
                int col  = (wv * 2 + ct2) * 16 + mrow;
                float bb = bl_s[col] + bp[col];
#pragma unroll
                for (int rt = 0; rt < 4; ++rt) {
#pragma unroll
                    for (int r = 0; r < 4; ++r) {
                        int grow = row0 + rt * 16 + hi * 4 + r;
                        if (grow < NSs)
                            out_s[(size_t)grow * DD + col] = 0.5f * (acc[rt][ct2][r] + bb);
                    }
                }
            }
        }
        if (xsb_out) { // l=0: bf16 table only, LDS-staged -> coalesced 16B
            __syncthreads();           // done reading A for MFMA
            __bf16* S = &A[0][0];
#pragma unroll
            for (int ct2 = 0; ct2 < 2; ++ct2) {
                int col  = (wv * 2 + ct2) * 16 + mrow;
                int cch  = col >> 3;
                int cin  = (col & 7) * 2;
                float bb = bl_s[col] + bp[col];
#pragma unroll
                for (int rt = 0; rt < 4; ++rt) {
#pragma unroll
                    for (int r = 0; r < 4; ++r) {
                        int lrow = rt * 16 + hi * 4 + r;
                        float v = 0.5f * (acc[rt][ct2][r] + bb);
                        *(__bf16*)((char*)S + lrow * 256 +
                                   (((cch ^ (lrow & 15)) << 4) | cin)) = (__bf16)v;
                    }
                }
            }
            __syncthreads();
            char* dst = (char*)xsb_out + (size_t)row0 * 256;   // +64 rows pad
#pragma unroll
            for (int k = 0; k < 4; ++k) {
                int o = tid * 16 + k * 4096;
                *(bf16x8*)(dst + o) = *(const bf16x8*)((const char*)S + o);
            }
        }
    } else {
        // ---------------- item path ----------------
        int row0 = (blockIdx.x - nb_stu) * BM;
        {
            const char* ga = (const char*)aggb_i + (size_t)row0 * 256 + lane * 16;
            const char* gx = (const char*)xib    + (size_t)row0 * 256 + lane * 16;
#pragma unroll
            for (int j = 0; j < 4; ++j) {
                int ch = (wv * 4 + j) * 1024;
                async_copy16((char*)A[0] + ch, ga + ch);
                async_copy16((char*)A[1] + ch, gx + ch);
            }
        }
        asm volatile("s_waitcnt vmcnt(0)" ::: "memory");
        __syncthreads();

        floatx4 acc[4][2];
#pragma unroll
        for (int a = 0; a < 4; ++a) {
            acc[a][0] = (floatx4){0.f, 0.f, 0.f, 0.f};
            acc[a][1] = (floatx4){0.f, 0.f, 0.f, 0.f};
        }
        const __bf16* Ws[2] = {Wl_i, Wr_i};
#pragma unroll
        for (int m = 0; m < 2; ++m) {
            bf16x8 bfr[2][4];
#pragma unroll
            for (int ct2 = 0; ct2 < 2; ++ct2) {
                int brow = (wv * 2 + ct2) * 16 + mrow;
#pragma unroll
                for (int kc = 0; kc < 4; ++kc)
                    bfr[ct2][kc] = *(const bf16x8*)(Ws[m] + (size_t)brow * DD + kc * 32 + hi * 8);
            }
            const char* Ab = (const char*)A[m];
#pragma unroll
            for (int rt = 0; rt < 4; ++rt) {
                const char* Ar = Ab + (rt * 16 + mrow) * 256;
#pragma unroll
                for (int kc = 0; kc < 4; ++kc) {
                    bf16x8 afr = *(const bf16x8*)(Ar + (((kc * 4 + hi) ^ mrow) << 4));
                    acc[rt][0] = __builtin_amdgcn_mfma_f32_16x16x32_bf16(afr, bfr[0][kc], acc[rt][0], 0, 0, 0);
                    acc[rt][1] = __builtin_amdgcn_mfma_f32_16x16x32_bf16(afr, bfr[1][kc], acc[rt][1], 0, 0, 0);
                }
            }
        }

#pragma unroll
        for (int ct2 = 0; ct2 < 2; ++ct2) {
            int col  = (wv * 2 + ct2) * 16 + mrow;
            float bb = bl_i[col];
            float s = 0.f, s2 = 0.f;
#pragma unroll
            for (int rt = 0; rt < 4; ++rt) {
#pragma unroll
                for (int r = 0; r < 4; ++r) {
                    int grow = row0 + rt * 16 + hi * 4 + r;
                    if (grow < NIi) {
                        float vv = acc[rt][ct2][r] + bb;
                        vv = (vv > 0.f) ? vv : expm1f(vv);
                        out_i[(size_t)grow * DD + col] = vv;
                        s += vv; s2 += vv * vv;
                    }
                }
            }
            // reduce across the 4 hi-groups (lanes mrow,+16,+32,+48): same col
            s  += __shfl_xor(s, 16);  s2 += __shfl_xor(s2, 16);
            s  += __shfl_xor(s, 32);  s2 += __shfl_xor(s2, 32);
            if (hi == 0) {
                atomicAdd(col_sum  + col, s);
                atomicAdd(col_sum2 + col, s2);
            }
        }
    }
}

// ---------------------------------------------------------------------------
// BN normalize: mean/rsqrt finalized inline from fused column sums.
// l=0: writes only the next layer's bf16 swizzled item table.
// l=1: writes only the f32 output.
// ---------------------------------------------------------------------------
__global__ __launch_bounds__(256) void bn_norm(
    const float* __restrict__ x,
    const float* __restrict__ cs,
    const float* __restrict__ cs2,
    const float* __restrict__ g,
    const float* __restrict__ b,
    float* out,                         // null at l=0
    __bf16* xib_out,                    // null at l=1
    int M)
{
    int i = blockIdx.x * 256 + threadIdx.x;
    if (i >= M * 32) return;
    int row = i >> 5;
    int h   = i & 31;                   // 8B half-chunk within row
    int c4  = h << 2;
    float invM = 1.0f / (float)M;
    floatx4 v = *(const floatx4*)(x + (size_t)row * DD + c4);
    floatx4 o;
#pragma unroll
    for (int k = 0; k < 4; ++k) {
        float m = cs[c4 + k] * invM;
        float r = rsqrtf(cs2[c4 + k] * invM - m * m + 1e-5f);
        o[k] = (v[k] - m) * r * g[c4 + k] + b[c4 + k];
    }
    if (out)
        *(floatx4*)(out + (size_t)row * DD + c4) = o;
    if (xib_out) {
        bf16x4 ob = { (__bf16)o.x, (__bf16)o.y, (__bf16)o.z, (__bf16)o.w };
        int phys = (((h >> 1) ^ (row & 15)) << 4) | ((h & 1) << 3);
        *(bf16x4*)((char*)xib_out + (size_t)row * 256 + phys) = ob;
    }
}

// ---------------------------------------------------------------------------
extern "C" void kernel_launch(void* const* d_in, const int* in_sizes, int n_in,
                              void* d_out, int out_size, void* d_ws, size_t ws_size,
                              hipStream_t stream)
{
    const float* x_student = (const float*)d_in[0];
    const float* x_item    = (const float*)d_in[1];
    const float* Wl_ri     = (const float*)d_in[2];
    const float* bl_ri     = (const float*)d_in[3];
    const float* Wr_ri     = (const float*)d_in[4];
    const float* Wl_rs     = (const float*)d_in[5];
    const float* bl_rs     = (const float*)d_in[6];
    const float* Wr_rs     = (const float*)d_in[7];
    const float* W_p       = (const float*)d_in[8];
    const float* b_p       = (const float*)d_in[9];
    const float* bn_g      = (const float*)d_in[10];
    const float* bn_b      = (const float*)d_in[11];
    const int* resp_src = (const int*)d_in[12];
    const int* resp_dst = (const int*)d_in[13];
    const int* rev_src  = (const int*)d_in[14];
    const int* rev_dst  = (const int*)d_in[15];
    const int* prec_src = (const int*)d_in[16];
    const int* prec_dst = (const int*)d_in[17];

    // ---- workspace ----
    char* ws = (char*)d_ws;
    size_t off = 0;
    auto alloc = [&](size_t bytes) -> void* {
        void* p = ws + off;
        off += (bytes + 1023) & ~(size_t)1023;
        return p;
    };
    // zeroed region: CSR counts + totals + fused BN column stats (per layer)
    int* cnt_r  = (int*)alloc(NIi * 4);
    int* cnt_v  = (int*)alloc(NSs * 4);
    int* cnt_p  = (int*)alloc(NSs * 4);
    int* totals = (int*)alloc(3 * 4);
    float* cstat = (float*)alloc(4 * 128 * 4);   // [l0 sum|l0 sum2|l1 sum|l1 sum2]
    size_t zero_bytes = off;
    // CSR arrays
    int* start_r = (int*)alloc(NIi * 4);
    int* fill_r  = (int*)alloc(NIi * 4);
    int* start_v = (int*)alloc(NSs * 4);
    int* fill_v  = (int*)alloc(NSs * 4);
    int* start_p = (int*)alloc(NSs * 4);
    int* fill_p  = (int*)alloc(NSs * 4);
    int* eidx_r  = (int*)alloc((size_t)E1e * 4);
    int* eidx_v  = (int*)alloc((size_t)E1e * 4);
    int* eidx_p  = (int*)alloc((size_t)E2e * 4);
    // bf16 swizzled tables & aggregation buffers (+64 rows pad for the last
    // GEMM block's async-stage / table-write overrun).
    __bf16* xsb    = (__bf16*)alloc((size_t)(NSs + 64) * DD * 2);  // 25.6 MB
    __bf16* xib    = (__bf16*)alloc((size_t)(NIi + 64) * DD * 2);  //  5.1 MB
    __bf16* aggb_s = (__bf16*)alloc((size_t)(NSs + 64) * DD * 2);  // 25.6 MB
    __bf16* simb_s = (__bf16*)alloc((size_t)(NSs + 64) * DD * 2);  // 25.6 MB
    __bf16* aggb_i = (__bf16*)alloc((size_t)(NIi + 64) * DD * 2);  //  5.1 MB
    __bf16* wbf  = (__bf16*)alloc((size_t)5 * 32768 * 2);
    // xi_tmp is now a DEDICATED buffer: with the fused GEMM dispatch, item
    // blocks write xi_tmp while stu blocks may still be reading aggb_s.
    float* xi_tmp = (float*)alloc((size_t)NIi * DD * 4);           // 10.24 MB
    (void)ws_size; (void)in_sizes; (void)n_in; (void)out_size;

    float* out_xi = (float*)d_out;                    // xi_2
    float* out_xs = out_xi + (size_t)NIi * DD;        // xs_2

    const int he1 = (E1e + 255) / 256, he2 = (E2e + 255) / 256;
    const int tni = (NIi + 255) / 256, tns = (NSs + 255) / 256;
    const int nb_i = (int)(((long)NIi * 32 + 255) / 256);   // 2500
    const int nb_v = (int)(((long)NSs * 32 + 255) / 256);   // 12500
    const int nb_p = nb_v;                                  // 12500
    const int gi_blocks  = (NIi + BM - 1) / BM;             // 313
    const int gs_blocks  = (NSs + BM - 1) / BM;             // 1563
    const int bnn_blocks = (NIi * 32 + 255) / 256;
    const int cxs_blocks = (NSs * 16 + 255) / 256;
    const int cxi_blocks = (NIi * 16 + 255) / 256;

    cvt_weights<<<640, 256, 0, stream>>>(Wl_ri, Wr_ri, Wl_rs, Wr_rs, W_p, wbf);
    __bf16* wb_l_ri = wbf + 0 * 32768;
    __bf16* wb_r_ri = wbf + 1 * 32768;
    __bf16* wb_l_rs = wbf + 2 * 32768;
    __bf16* wb_r_rs = wbf + 3 * 32768;
    __bf16* wb_p    = wbf + 4 * 32768;

    // layer-0 bf16 swizzled node tables
    cvt_x<<<cxs_blocks, 256, 0, stream>>>(x_student, xsb, NSs);
    cvt_x<<<cxi_blocks, 256, 0, stream>>>(x_item,    xib, NIi);

    // ---- CSR build (once per call, shared by both layers) ----
    hipMemsetAsync(ws, 0, zero_bytes, stream);
    hist_kernel<<<he1, 256, 0, stream>>>(resp_dst, cnt_r, E1e);
    hist_kernel<<<he1, 256, 0, stream>>>(rev_dst,  cnt_v, E1e);
    hist_kernel<<<he2, 256, 0, stream>>>(prec_dst, cnt_p, E2e);
    ticket_kernel<<<tni, 256, 0, stream>>>(cnt_r, start_r, fill_r, totals + 0, NIi);
    ticket_kernel<<<tns, 256, 0, stream>>>(cnt_v, start_v, fill_v, totals + 1, NSs);
    ticket_kernel<<<tns, 256, 0, stream>>>(cnt_p, start_p, fill_p, totals + 2, NSs);
    fill_kernel<<<he1, 256, 0, stream>>>(resp_src, resp_dst, fill_r, eidx_r, E1e);
    fill_kernel<<<he1, 256, 0, stream>>>(rev_src,  rev_dst,  fill_v, eidx_v, E1e);
    fill_kernel<<<he2, 256, 0, stream>>>(prec_src, prec_dst, fill_p, eidx_p, E2e);

    for (int l = 0; l < 2; l++) {
        size_t wOfs = (size_t)l * DD * DD;
        size_t bOfs = (size_t)l * DD;
        float* cs  = cstat + (size_t)l * 256;
        float* cs2 = cs + 128;
        __bf16* xsb_next = (l == 0) ? xsb : nullptr;   // fused epilogue table
        __bf16* xib_next = (l == 0) ? xib : nullptr;
        float* f32_xs    = (l == 0) ? nullptr : out_xs; // l=0 f32 is dead
        float* f32_xi    = (l == 0) ? nullptr : out_xi;

        gather3<<<nb_i + nb_v + nb_p, 256, 0, stream>>>(
            xsb, xib,
            start_r, fill_r, eidx_r,
            start_v, fill_v, eidx_v,
            start_p, fill_p, eidx_p,
            aggb_i, aggb_s, simb_s, nb_i, nb_v);

        // fused stu+item GEMM. l==0 stu path reads xsb rows [row0,row0+64)
        // then overwrites only those rows (after vmcnt0+barrier) -> safe.
        gemm_fused<<<gs_blocks + gi_blocks, 256, 0, stream>>>(
            aggb_s, xsb, simb_s,
            wb_l_rs + wOfs, wb_r_rs + wOfs, wb_p + wOfs,
            bl_rs + bOfs, b_p + bOfs,
            f32_xs, xsb_next,
            aggb_i, xib,
            wb_l_ri + wOfs, wb_r_ri + wOfs, bl_ri + bOfs,
            xi_tmp, cs, cs2,
            gs_blocks);

        bn_norm<<<bnn_blocks, 256, 0, stream>>>(xi_tmp, cs, cs2,
                                                bn_g + bOfs, bn_b + bOfs,
                                                f32_xi, xib_next, NIi);
    }
}